// Round 4
// baseline (303.927 us; speedup 1.0000x reference)
//
#include <hip/hip_runtime.h>
#include <hip/hip_bf16.h>
#include <math.h>
#include <float.h>

#define B       32
#define S_CURR  128
#define D       512
#define H       8
#define DH      64
#define NM      16
#define NCAND   39998          // emb[2:]
#define MG      (B * NM)       // 512 gathered rows
#define SCLD    40064          // padded row count of embB / col stride of scB
#define NT      313            // ceil(NCAND/128) N-tiles

typedef __bf16 bf16x8_t __attribute__((ext_vector_type(8)));
typedef __bf16 bf16x4_t __attribute__((ext_vector_type(4)));
typedef float  f32x4_t  __attribute__((ext_vector_type(4)));

typedef __attribute__((address_space(3))) unsigned int lds_u32_t;
typedef const __attribute__((address_space(1))) unsigned int gbl_u32_t;

__device__ __forceinline__ void async16(const void* g, void* l) {
    __builtin_amdgcn_global_load_lds((gbl_u32_t*)g, (lds_u32_t*)l, 16, 0, 0);
}

// ---------------------------------------------------------------------------
// Prep kernel: bx < 10512 -> f32->bf16 converts (emb[2:], 4 weight mats);
// 10512 <= bx < 14608 -> currB = bf16(emb[idx]+pe); bx == 14608 -> qidx.
// ---------------------------------------------------------------------------
__global__ __launch_bounds__(256) void prep_kernel(
    const float* __restrict__ emb,
    const float* __restrict__ wq, const float* __restrict__ wk,
    const float* __restrict__ wv, const float* __restrict__ t2w,
    __bf16* __restrict__ embB, __bf16* __restrict__ wqB, __bf16* __restrict__ wkB,
    __bf16* __restrict__ wvB, __bf16* __restrict__ t2wB,
    const int* __restrict__ curr_idx, __bf16* __restrict__ currB,
    const int* __restrict__ mask_pos, int* __restrict__ qidx)
{
    int bx = blockIdx.x;
    if (bx < 10512) {
        const float* src; __bf16* dst; size_t n, base;
        if (bx < 10000) {
            src = emb + 2 * D; dst = embB; n = (size_t)NCAND * D; base = (size_t)bx * 2048;
        } else {
            int w = (bx - 10000) >> 7;
            base = (size_t)((bx - 10000) & 127) * 2048;
            n = (size_t)D * D;
            src = (w == 0) ? wq : (w == 1) ? wk : (w == 2) ? wv : t2w;
            dst = (w == 0) ? wqB : (w == 1) ? wkB : (w == 2) ? wvB : t2wB;
        }
        size_t i = base + (size_t)threadIdx.x * 8;
        if (i >= n) return;
        float4 a = *(const float4*)(src + i);
        float4 b = *(const float4*)(src + i + 4);
        bf16x8_t v;
        v[0] = (__bf16)a.x; v[1] = (__bf16)a.y; v[2] = (__bf16)a.z; v[3] = (__bf16)a.w;
        v[4] = (__bf16)b.x; v[5] = (__bf16)b.y; v[6] = (__bf16)b.z; v[7] = (__bf16)b.w;
        *(bf16x8_t*)(dst + i) = v;
        return;
    }
    if (bx == 14608) {
        int r = threadIdx.x;
        qidx[r] = (r >> 4) * S_CURR + mask_pos[r];
        r += 256;
        qidx[r] = (r >> 4) * S_CURR + mask_pos[r];
        return;
    }
    int bs = bx - 10512;
    int s = bs & (S_CURR - 1);
    int g = curr_idx[bs];
    const float* e = emb + (size_t)g * D;
    __bf16* o = currB + (size_t)bs * D;
    int d = threadIdx.x * 2;
    float div = expf(-(float)d * (9.210340371976184f / 512.0f));
    float ang = (float)s * div;
    o[d]     = (__bf16)(e[d]     + sinf(ang));
    o[d + 1] = (__bf16)(e[d + 1] + cosf(ang));
}

// ---------------------------------------------------------------------------
// bf16 GEMM, swizzled-LDS, double-buffered counted-vmcnt prefetch.
// C = A @ W^T + bias, K=512, N=512.
// SWAPPED-OPERAND MFMA: mfma(bfv, af) puts the N index on the register axis
// (lane owns 4 consecutive output cols at one row) -> bf16x4 vectorized C
// stores + float4 bias loads. Fragment staging/loads unchanged.
// ---------------------------------------------------------------------------
__global__ __launch_bounds__(256) void gemm_bf(
    const __bf16* __restrict__ A,
    const __bf16* __restrict__ W0, const float* __restrict__ b0, __bf16* __restrict__ C0,
    const __bf16* __restrict__ W1, const float* __restrict__ b1, __bf16* __restrict__ C1,
    const __bf16* __restrict__ W2, const float* __restrict__ b2, __bf16* __restrict__ C2,
    const int* __restrict__ rowidx)
{
    const int z = blockIdx.z;
    if (z == 2 && blockIdx.x >= 4) return;   // Q problem has M=512 only
    const __bf16* W = (z == 0) ? W0 : (z == 1) ? W1 : W2;
    const float* bias = (z == 0) ? b0 : (z == 1) ? b1 : b2;
    __bf16* C = (z == 0) ? C0 : (z == 1) ? C1 : C2;

    __shared__ __bf16 As[2][128 * 64];
    __shared__ __bf16 Bs[2][128 * 64];

    const int tid = threadIdx.x, lane = tid & 63, wave = tid >> 6;
    const int wy = wave >> 1, wx = wave & 1;
    const int m0 = blockIdx.x * 128, n0 = blockIdx.y * 128;
    const int lrow = lane >> 3;
    const int lcol = (((lane & 7) ^ lrow) & 7) * 8;   // swizzled source column

    const __bf16* aptr[4]; const __bf16* bptr[4];
#pragma unroll
    for (int i = 0; i < 4; ++i) {
        int chunk = wave * 4 + i;
        int ar = m0 + chunk * 8 + lrow;
        if (z == 2) ar = rowidx[ar];
        aptr[i] = A + (size_t)ar * 512 + lcol;
        bptr[i] = W + (size_t)(n0 + chunk * 8 + lrow) * 512 + lcol;
    }

    f32x4_t acc[4][4];
#pragma unroll
    for (int i = 0; i < 4; ++i)
#pragma unroll
        for (int j = 0; j < 4; ++j) acc[i][j] = (f32x4_t){0.f, 0.f, 0.f, 0.f};

    const int l7 = lane & 7, quad = lane >> 4, c16 = lane & 15;

    // prologue: stage K-step 0 into buffer 0
#pragma unroll
    for (int i = 0; i < 4; ++i) {
        int chunk = wave * 4 + i;
        async16(aptr[i], &As[0][chunk * 512]);
        async16(bptr[i], &Bs[0][chunk * 512]);
    }

#pragma unroll
    for (int t = 0; t < 8; ++t) {
        const int cur = t & 1;
        if (t < 7) {
            const int kk = (t + 1) * 64;
#pragma unroll
            for (int i = 0; i < 4; ++i) {
                int chunk = wave * 4 + i;
                async16(aptr[i] + kk, &As[cur ^ 1][chunk * 512]);
                async16(bptr[i] + kk, &Bs[cur ^ 1][chunk * 512]);
            }
            asm volatile("s_waitcnt vmcnt(8)" ::: "memory");
        } else {
            asm volatile("s_waitcnt vmcnt(0)" ::: "memory");
        }
        __builtin_amdgcn_s_barrier();
#pragma unroll
        for (int kb = 0; kb < 2; ++kb) {
            const int goff = (((kb * 4 + quad) ^ l7)) * 8;
            bf16x8_t af[4], bfv[4];
#pragma unroll
            for (int i = 0; i < 4; ++i)
                af[i] = *(const bf16x8_t*)&As[cur][(wy * 64 + i * 16 + c16) * 64 + goff];
#pragma unroll
            for (int j = 0; j < 4; ++j)
                bfv[j] = *(const bf16x8_t*)&Bs[cur][(wx * 64 + j * 16 + c16) * 64 + goff];
#pragma unroll
            for (int i = 0; i < 4; ++i)
#pragma unroll
                for (int j = 0; j < 4; ++j)
                    acc[i][j] = __builtin_amdgcn_mfma_f32_16x16x32_bf16(
                        bfv[j], af[i], acc[i][j], 0, 0, 0);   // swapped: rows=N, cols=M
        }
        asm volatile("s_waitcnt lgkmcnt(0)" ::: "memory");
        __builtin_amdgcn_s_barrier();   // protect buf[cur] from next stage
    }

    // Swapped C/D layout: per (i,j) a lane holds cols colb..colb+3 of row
    // (m0 + wy*64 + i*16 + c16). Vectorized bf16x4 stores, float4 bias.
#pragma unroll
    for (int i = 0; i < 4; ++i) {
        const int row = m0 + wy * 64 + i * 16 + c16;
#pragma unroll
        for (int j = 0; j < 4; ++j) {
            const int colb = n0 + wx * 64 + j * 16 + quad * 4;
            float4 bv = *(const float4*)&bias[colb];
            bf16x4_t o;
            o[0] = (__bf16)(acc[i][j][0] + bv.x);
            o[1] = (__bf16)(acc[i][j][1] + bv.y);
            o[2] = (__bf16)(acc[i][j][2] + bv.z);
            o[3] = (__bf16)(acc[i][j][3] + bv.w);
            *(bf16x4_t*)&C[(size_t)row * 512 + colb] = o;
        }
    }
}

// ---------------------------------------------------------------------------
// Scores GEMM + softmax partials. A (512x512, L2-resident) fragments loaded
// DIRECTLY global->register (no LDS round-trip: the old swizzled-LDS path
// delivered exactly global col kb*32+quad*8 to each lane, so a 16B global
// load at that address is a drop-in MFMA operand). LDS is B-only, TRIPLE-
// buffered: depth-2 prefetch, counted vmcnt. 50 KB LDS -> 3 blocks/CU.
// ---------------------------------------------------------------------------
__global__ __launch_bounds__(256) void gemm_scores(
    const __bf16* __restrict__ A,      // 512 x 512 (gatheredB)
    const __bf16* __restrict__ Bm,     // 40064(pad) x 512 (embB)
    __bf16* __restrict__ scB,          // 512 x SCLD
    float* __restrict__ pmax, float* __restrict__ psum)
{
    const int bid = blockIdx.x;
    const int xcd = bid & 7, k = bid >> 3;       // k: 0..159
    const int nt = xcd * 40 + (k >> 2);
    if (nt >= NT) return;
    const int m0 = (k & 3) * 128, n0 = nt * 128;

    __shared__ __bf16 Bs[3][128 * 64];
    __shared__ float redm[2][128], reds[2][128];

    const int tid = threadIdx.x, lane = tid & 63, wave = tid >> 6;
    const int wy = wave >> 1, wx = wave & 1;
    const int lrow = lane >> 3;
    const int lcol = (((lane & 7) ^ lrow) & 7) * 8;
    const int l7 = lane & 7, quad = lane >> 4, c16 = lane & 15;

    const __bf16* bptr[4];
#pragma unroll
    for (int i = 0; i < 4; ++i)
        bptr[i] = Bm + (size_t)(n0 + (wave * 4 + i) * 8 + lrow) * 512 + lcol;

    // per-lane A fragment base: row m0+wy*64+i*16+c16, col quad*8
    const __bf16* arow[4];
#pragma unroll
    for (int i = 0; i < 4; ++i)
        arow[i] = A + (size_t)(m0 + wy * 64 + i * 16 + c16) * 512 + quad * 8;

    f32x4_t acc[4][4];
#pragma unroll
    for (int i = 0; i < 4; ++i)
#pragma unroll
        for (int j = 0; j < 4; ++j) acc[i][j] = (f32x4_t){0.f, 0.f, 0.f, 0.f};

    // prologue: stage B(0)->buf0, B(1)->buf1
#pragma unroll
    for (int i = 0; i < 4; ++i)
        async16(bptr[i], &Bs[0][(wave * 4 + i) * 512]);
#pragma unroll
    for (int i = 0; i < 4; ++i)
        async16(bptr[i] + 64, &Bs[1][(wave * 4 + i) * 512]);

#pragma unroll
    for (int t = 0; t < 8; ++t) {
        const int cur = t % 3;
        // A fragments for this step: 8x 16B global loads (L2-hot)
        bf16x8_t af[4][2];
#pragma unroll
        for (int i = 0; i < 4; ++i)
#pragma unroll
            for (int kb = 0; kb < 2; ++kb)
                af[i][kb] = *(const bf16x8_t*)(arow[i] + t * 64 + kb * 32);
        if (t < 6) {
#pragma unroll
            for (int i = 0; i < 4; ++i)
                async16(bptr[i] + (t + 2) * 64, &Bs[(t + 2) % 3][(wave * 4 + i) * 512]);
            asm volatile("s_waitcnt vmcnt(8)" ::: "memory");
        } else if (t == 6) {
            asm volatile("s_waitcnt vmcnt(4)" ::: "memory");
        } else {
            asm volatile("s_waitcnt vmcnt(0)" ::: "memory");
        }
        __builtin_amdgcn_s_barrier();
#pragma unroll
        for (int kb = 0; kb < 2; ++kb) {
            const int goff = (((kb * 4 + quad) ^ l7)) * 8;
            bf16x8_t bfv[4];
#pragma unroll
            for (int j = 0; j < 4; ++j)
                bfv[j] = *(const bf16x8_t*)&Bs[cur][(wx * 64 + j * 16 + c16) * 64 + goff];
#pragma unroll
            for (int i = 0; i < 4; ++i)
#pragma unroll
                for (int j = 0; j < 4; ++j)
                    acc[i][j] = __builtin_amdgcn_mfma_f32_16x16x32_bf16(
                        bfv[j], af[i][kb], acc[i][j], 0, 0, 0);   // swapped: rows=N, cols=M
        }
        asm volatile("s_waitcnt lgkmcnt(0)" ::: "memory");
        __builtin_amdgcn_s_barrier();   // protect Bs[cur] from later stages
    }

    // Epilogue: lane's 16 values all lie in row (m0+wy*64+i*16+c16);
    // cols n0+wx*64+j*16+quad*4 .. +3.  Lane-local softmax partials, then
    // cross-n lane combine (xor 16,32), then cross-wx combine via LDS.
    const bool tailb = (n0 + 128 > NCAND);
#pragma unroll
    for (int i = 0; i < 4; ++i) {
        const int lrw = wy * 64 + i * 16 + c16;       // tile-local row
        const size_t rowbase = (size_t)(m0 + lrw) * SCLD;
        float vs[4][4];
        float vmax = -FLT_MAX;
        float ssum = 0.f;
        if (!tailb) {
#pragma unroll
            for (int j = 0; j < 4; ++j) {
                const int nb = n0 + wx * 64 + j * 16 + quad * 4;
                bf16x4_t o;
#pragma unroll
                for (int rr = 0; rr < 4; ++rr) {
                    __bf16 xb = (__bf16)acc[i][j][rr];
                    o[rr] = xb;
                    float xr = (float)xb;
                    vs[j][rr] = xr;
                    vmax = fmaxf(vmax, xr);
                }
                *(bf16x4_t*)&scB[rowbase + nb] = o;
            }
#pragma unroll
            for (int j = 0; j < 4; ++j)
#pragma unroll
                for (int rr = 0; rr < 4; ++rr)
                    ssum += __expf(vs[j][rr] - vmax);
        } else {
            for (int j = 0; j < 4; ++j) {
                const int nb = n0 + wx * 64 + j * 16 + quad * 4;
                for (int rr = 0; rr < 4; ++rr) {
                    const int n = nb + rr;
                    __bf16 xb = (__bf16)acc[i][j][rr];
                    float xr = (float)xb;
                    if (n < NCAND) {
                        scB[rowbase + n] = xb;
                        vs[j][rr] = xr;
                        vmax = fmaxf(vmax, xr);
                    } else vs[j][rr] = -FLT_MAX;
                }
            }
            for (int j = 0; j < 4; ++j)
                for (int rr = 0; rr < 4; ++rr)
                    ssum += (vs[j][rr] > -FLT_MAX) ? __expf(vs[j][rr] - vmax) : 0.f;
        }
        // combine lanes {c16, c16+16, c16+32, c16+48} (same row, different n)
#pragma unroll
        for (int mk = 16; mk < 64; mk <<= 1) {
            float om = __shfl_xor(vmax, mk);
            float os = __shfl_xor(ssum, mk);
            float mm = fmaxf(vmax, om);
            ssum = ssum * __expf(vmax - mm) + os * __expf(om - mm);
            vmax = mm;
        }
        if (quad == 0) { redm[wx][lrw] = vmax; reds[wx][lrw] = ssum; }
    }
    __syncthreads();
    if (tid < 128) {
        float ma = redm[0][tid], sa = reds[0][tid];
        float mb = redm[1][tid], sb = reds[1][tid];
        float mm = fmaxf(ma, mb);
        float ss = sa * __expf(ma - mm) + sb * __expf(mb - mm);
        pmax[(size_t)(m0 + tid) * NT + nt] = mm;     // [row][nt] layout
        psum[(size_t)(m0 + tid) * NT + nt] = ss;
    }
}

// ---------------------------------------------------------------------------
// Attention: one block per (b,h); K/V/Q head-slices staged in LDS once.
// 256 threads = 16 queries x 16 lanes. tanh fused at write.
// ---------------------------------------------------------------------------
#define KPAD 72
__global__ __launch_bounds__(256) void attn_kernel(const __bf16* __restrict__ Qg,
                                                   const __bf16* __restrict__ K,
                                                   const __bf16* __restrict__ V,
                                                   __bf16* __restrict__ attnB) {
    const int b = blockIdx.x, h = blockIdx.y, t = threadIdx.x;
    __shared__ __bf16 Ks[128 * KPAD];
    __shared__ __bf16 Vs[128 * KPAD];
    __shared__ float  Qs[16 * 68];
    __shared__ float  P[16 * 130];

    for (int i = t; i < 1024; i += 256) {
        int row = i >> 3, cg = (i & 7) * 8;
        size_t gsrc = ((size_t)(b * S_CURR + row)) * D + h * DH + cg;
        *(bf16x8_t*)&Ks[row * KPAD + cg] = *(const bf16x8_t*)&K[gsrc];
        *(bf16x8_t*)&Vs[row * KPAD + cg] = *(const bf16x8_t*)&V[gsrc];
    }
    if (t < 128) {
        int q = t >> 3, cg = (t & 7) * 8;
        bf16x8_t qv = *(const bf16x8_t*)&Qg[((size_t)(b * NM + q)) * D + h * DH + cg];
#pragma unroll
        for (int u = 0; u < 8; ++u) Qs[q * 68 + cg + u] = (float)qv[u];
    }
    __syncthreads();

    const int q = t >> 4, i = t & 15;
    float sv[8];
    float lmax = -FLT_MAX;
#pragma unroll
    for (int z = 0; z < 8; ++z) {
        int kk = i + z * 16;
        float s = 0.f;
#pragma unroll
        for (int d0 = 0; d0 < DH; d0 += 8) {
            bf16x8_t kv = *(const bf16x8_t*)&Ks[kk * KPAD + d0];
#pragma unroll
            for (int u = 0; u < 8; ++u) s += Qs[q * 68 + d0 + u] * (float)kv[u];
        }
        sv[z] = s; lmax = fmaxf(lmax, s);
    }
#pragma unroll
    for (int mk = 1; mk < 16; mk <<= 1) lmax = fmaxf(lmax, __shfl_xor(lmax, mk));
    float lsum = 0.f;
#pragma unroll
    for (int z = 0; z < 8; ++z) {
        float e = __expf(sv[z] - lmax);
        P[q * 130 + i + z * 16] = e;
        lsum += e;
    }
#pragma unroll
    for (int mk = 1; mk < 16; mk <<= 1) lsum += __shfl_xor(lsum, mk);
    const float inv = 1.0f / lsum;

    // P[q][*] produced and consumed by the same wave (q-group within wave) —
    // wave-order LDS semantics make this safe without a block barrier.
    const int d = i * 4;
    float a0 = 0.f, a1 = 0.f, a2 = 0.f, a3 = 0.f;
    for (int kk = 0; kk < 128; ++kk) {
        float p = P[q * 130 + kk];
        bf16x4_t vv = *(const bf16x4_t*)&Vs[kk * KPAD + d];
        a0 += p * (float)vv[0]; a1 += p * (float)vv[1];
        a2 += p * (float)vv[2]; a3 += p * (float)vv[3];
    }
    __bf16* o = attnB + ((size_t)(b * NM + q)) * D + h * DH + d;
    o[0] = (__bf16)tanhf(a0 * inv); o[1] = (__bf16)tanhf(a1 * inv);
    o[2] = (__bf16)tanhf(a2 * inv); o[3] = (__bf16)tanhf(a3 * inv);
}

// ---------------------------------------------------------------------------
__global__ __launch_bounds__(256) void lse_reduce(const float* __restrict__ pmax,
                                                  const float* __restrict__ psum,
                                                  float* __restrict__ lse) {
    int row = blockIdx.x, t = threadIdx.x;
    float m = -FLT_MAX, s = 0.f;
    for (int i = t; i < NT; i += 256) {
        float om = pmax[(size_t)row * NT + i];       // [row][nt]: coalesced
        float os = psum[(size_t)row * NT + i];
        float mm = fmaxf(m, om);
        s = s * __expf(m - mm) + os * __expf(om - mm);
        m = mm;
    }
    __shared__ float ms[256], ss[256];
    ms[t] = m; ss[t] = s;
    __syncthreads();
    for (int off = 128; off > 0; off >>= 1) {
        if (t < off) {
            float m1 = ms[t], s1 = ss[t], m2 = ms[t + off], s2 = ss[t + off];
            float mm = fmaxf(m1, m2);
            ms[t] = mm;
            ss[t] = s1 * __expf(m1 - mm) + s2 * __expf(m2 - mm);
        }
        __syncthreads();
    }
    if (t == 0) lse[row] = ms[0] + logf(ss[0]);
}

// ---------------------------------------------------------------------------
__global__ __launch_bounds__(256) void final_out(const __bf16* __restrict__ scB,
                                                 const float* __restrict__ lse,
                                                 float* __restrict__ out) {
    int row = blockIdx.y;
    int c0 = (blockIdx.x * 256 + threadIdx.x) * 8;
    if (c0 >= NCAND) return;
    float l = lse[row];
    bf16x8_t v = *(const bf16x8_t*)(scB + (size_t)row * SCLD + c0);
    float* o = out + (size_t)row * NCAND + c0;
    if (c0 + 8 <= NCAND) {
        *(float2*)(o)     = make_float2((float)v[0] - l, (float)v[1] - l);
        *(float2*)(o + 2) = make_float2((float)v[2] - l, (float)v[3] - l);
        *(float2*)(o + 4) = make_float2((float)v[4] - l, (float)v[5] - l);
        *(float2*)(o + 6) = make_float2((float)v[6] - l, (float)v[7] - l);
    } else {
        for (int k2 = 0; k2 < NCAND - c0; ++k2) o[k2] = (float)v[k2] - l;
    }
}

// ---------------------------------------------------------------------------
extern "C" void kernel_launch(void* const* d_in, const int* in_sizes, int n_in,
                              void* d_out, int out_size, void* d_ws, size_t ws_size,
                              hipStream_t stream) {
    const int*   mask_pos = (const int*)d_in[2];
    const int*   curr_idx = (const int*)d_in[3];
    const float* emb      = (const float*)d_in[5];
    const float* c_wq = (const float*)d_in[12];
    const float* c_bq = (const float*)d_in[13];
    const float* c_wk = (const float*)d_in[14];
    const float* c_bk = (const float*)d_in[15];
    const float* c_wv = (const float*)d_in[16];
    const float* c_bv = (const float*)d_in[17];
    const float* t2_w = (const float*)d_in[24];
    const float* t2_b = (const float*)d_in[25];
    float* out = (float*)d_out;

    char* w = (char*)d_ws;
    __bf16* embB  = (__bf16*)w;                           // 40064x512 bf16 = 41 MB
    __bf16* scB   = (__bf16*)(w + 41025536);              // 512x40064 bf16 = 41 MB
    __bf16* currB = scB;                                  // overlay (dead pre-scores)
    __bf16* Kf    = (__bf16*)(w + 41025536 + 4194304);
    __bf16* Vf    = (__bf16*)(w + 41025536 + 8388608);
    __bf16* Qg    = (__bf16*)(w + 41025536 + 12582912);
    __bf16* attnB = (__bf16*)(w + 41025536 + 13107200);
    __bf16* wqB   = (__bf16*)(w + 41025536 + 13631488);
    __bf16* wkB   = (__bf16*)(w + 41025536 + 14155776);
    __bf16* wvB   = (__bf16*)(w + 41025536 + 14680064);
    __bf16* t2wB  = (__bf16*)(w + 41025536 + 15204352);
    int*    qidx  = (int*)   (w + 41025536 + 15728640);
    __bf16* gatheredB = (__bf16*)(w + 82051072);
    float*  pmax  = (float*)(w + 82575360);
    float*  psum  = (float*)(w + 83216384);
    float*  lse   = (float*)(w + 83857408);

    hipLaunchKernelGGL(prep_kernel, dim3(14609), dim3(256), 0, stream,
                       emb, c_wq, c_wk, c_wv, t2_w, embB, wqB, wkB, wvB, t2wB,
                       curr_idx, currB, mask_pos, qidx);
    // K (z=0), V (z=1), Q-gathered (z=2, only 4 M-tiles) in one dispatch
    hipLaunchKernelGGL(gemm_bf, dim3(32, 4, 3), dim3(256), 0, stream,
                       currB, wkB, c_bk, Kf, wvB, c_bv, Vf, wqB, c_bq, Qg, qidx);
    hipLaunchKernelGGL(attn_kernel, dim3(B, H), dim3(256), 0, stream,
                       Qg, Kf, Vf, attnB);
    hipLaunchKernelGGL(gemm_bf, dim3(4, 4, 1), dim3(256), 0, stream,
                       attnB, t2wB, t2_b, gatheredB,
                       t2wB, t2_b, gatheredB, t2wB, t2_b, gatheredB,
                       (const int*)nullptr);
    hipLaunchKernelGGL(gemm_scores, dim3(1280), dim3(256), 0, stream,
                       gatheredB, embB, scB, pmax, psum);
    hipLaunchKernelGGL(lse_reduce, dim3(MG), dim3(256), 0, stream, pmax, psum, lse);
    hipLaunchKernelGGL(final_out, dim3(20, MG), dim3(256), 0, stream, scB, lse, out);
}

// Round 5
// 293.964 us; speedup vs baseline: 1.0339x; 1.0339x over previous
//
#include <hip/hip_runtime.h>
#include <hip/hip_bf16.h>
#include <math.h>
#include <float.h>

#define B       32
#define S_CURR  128
#define D       512
#define H       8
#define DH      64
#define NM      16
#define NCAND   39998          // emb[2:]
#define MG      (B * NM)       // 512 gathered rows
#define SCLD    40064          // padded row count of embB / col stride of scB
#define NT      313            // ceil(NCAND/128) N-tiles

typedef __bf16 bf16x8_t __attribute__((ext_vector_type(8)));
typedef __bf16 bf16x4_t __attribute__((ext_vector_type(4)));
typedef float  f32x4_t  __attribute__((ext_vector_type(4)));

typedef __attribute__((address_space(3))) unsigned int lds_u32_t;
typedef const __attribute__((address_space(1))) unsigned int gbl_u32_t;

__device__ __forceinline__ void async16(const void* g, void* l) {
    __builtin_amdgcn_global_load_lds((gbl_u32_t*)g, (lds_u32_t*)l, 16, 0, 0);
}

// ---------------------------------------------------------------------------
// Prep kernel: bx < 10512 -> f32->bf16 converts (emb[2:], 4 weight mats);
// 10512 <= bx < 14608 -> currB = bf16(emb[idx]+pe); bx == 14608 -> qidx.
// ---------------------------------------------------------------------------
__global__ __launch_bounds__(256) void prep_kernel(
    const float* __restrict__ emb,
    const float* __restrict__ wq, const float* __restrict__ wk,
    const float* __restrict__ wv, const float* __restrict__ t2w,
    __bf16* __restrict__ embB, __bf16* __restrict__ wqB, __bf16* __restrict__ wkB,
    __bf16* __restrict__ wvB, __bf16* __restrict__ t2wB,
    const int* __restrict__ curr_idx, __bf16* __restrict__ currB,
    const int* __restrict__ mask_pos, int* __restrict__ qidx)
{
    int bx = blockIdx.x;
    if (bx < 10512) {
        const float* src; __bf16* dst; size_t n, base;
        if (bx < 10000) {
            src = emb + 2 * D; dst = embB; n = (size_t)NCAND * D; base = (size_t)bx * 2048;
        } else {
            int w = (bx - 10000) >> 7;
            base = (size_t)((bx - 10000) & 127) * 2048;
            n = (size_t)D * D;
            src = (w == 0) ? wq : (w == 1) ? wk : (w == 2) ? wv : t2w;
            dst = (w == 0) ? wqB : (w == 1) ? wkB : (w == 2) ? wvB : t2wB;
        }
        size_t i = base + (size_t)threadIdx.x * 8;
        if (i >= n) return;
        float4 a = *(const float4*)(src + i);
        float4 b = *(const float4*)(src + i + 4);
        bf16x8_t v;
        v[0] = (__bf16)a.x; v[1] = (__bf16)a.y; v[2] = (__bf16)a.z; v[3] = (__bf16)a.w;
        v[4] = (__bf16)b.x; v[5] = (__bf16)b.y; v[6] = (__bf16)b.z; v[7] = (__bf16)b.w;
        *(bf16x8_t*)(dst + i) = v;
        return;
    }
    if (bx == 14608) {
        int r = threadIdx.x;
        qidx[r] = (r >> 4) * S_CURR + mask_pos[r];
        r += 256;
        qidx[r] = (r >> 4) * S_CURR + mask_pos[r];
        return;
    }
    int bs = bx - 10512;
    int s = bs & (S_CURR - 1);
    int g = curr_idx[bs];
    const float* e = emb + (size_t)g * D;
    __bf16* o = currB + (size_t)bs * D;
    int d = threadIdx.x * 2;
    float div = expf(-(float)d * (9.210340371976184f / 512.0f));
    float ang = (float)s * div;
    o[d]     = (__bf16)(e[d]     + sinf(ang));
    o[d + 1] = (__bf16)(e[d + 1] + cosf(ang));
}

// ---------------------------------------------------------------------------
// bf16 GEMM, swizzled-LDS, double-buffered counted-vmcnt prefetch.
// C = A @ W^T + bias, K=512, N=512.
// SWAPPED-OPERAND MFMA: mfma(bfv, af) puts the N index on the register axis
// (lane owns 4 consecutive output cols at one row) -> bf16x4 vectorized C
// stores + float4 bias loads. Fragment staging/loads unchanged.
// ---------------------------------------------------------------------------
__global__ __launch_bounds__(256) void gemm_bf(
    const __bf16* __restrict__ A,
    const __bf16* __restrict__ W0, const float* __restrict__ b0, __bf16* __restrict__ C0,
    const __bf16* __restrict__ W1, const float* __restrict__ b1, __bf16* __restrict__ C1,
    const __bf16* __restrict__ W2, const float* __restrict__ b2, __bf16* __restrict__ C2,
    const int* __restrict__ rowidx)
{
    const int z = blockIdx.z;
    if (z == 2 && blockIdx.x >= 4) return;   // Q problem has M=512 only
    const __bf16* W = (z == 0) ? W0 : (z == 1) ? W1 : W2;
    const float* bias = (z == 0) ? b0 : (z == 1) ? b1 : b2;
    __bf16* C = (z == 0) ? C0 : (z == 1) ? C1 : C2;

    __shared__ __bf16 As[2][128 * 64];
    __shared__ __bf16 Bs[2][128 * 64];

    const int tid = threadIdx.x, lane = tid & 63, wave = tid >> 6;
    const int wy = wave >> 1, wx = wave & 1;
    const int m0 = blockIdx.x * 128, n0 = blockIdx.y * 128;
    const int lrow = lane >> 3;
    const int lcol = (((lane & 7) ^ lrow) & 7) * 8;   // swizzled source column

    const __bf16* aptr[4]; const __bf16* bptr[4];
#pragma unroll
    for (int i = 0; i < 4; ++i) {
        int chunk = wave * 4 + i;
        int ar = m0 + chunk * 8 + lrow;
        if (z == 2) ar = rowidx[ar];
        aptr[i] = A + (size_t)ar * 512 + lcol;
        bptr[i] = W + (size_t)(n0 + chunk * 8 + lrow) * 512 + lcol;
    }

    f32x4_t acc[4][4];
#pragma unroll
    for (int i = 0; i < 4; ++i)
#pragma unroll
        for (int j = 0; j < 4; ++j) acc[i][j] = (f32x4_t){0.f, 0.f, 0.f, 0.f};

    const int l7 = lane & 7, quad = lane >> 4, c16 = lane & 15;

    // prologue: stage K-step 0 into buffer 0
#pragma unroll
    for (int i = 0; i < 4; ++i) {
        int chunk = wave * 4 + i;
        async16(aptr[i], &As[0][chunk * 512]);
        async16(bptr[i], &Bs[0][chunk * 512]);
    }

#pragma unroll
    for (int t = 0; t < 8; ++t) {
        const int cur = t & 1;
        if (t < 7) {
            const int kk = (t + 1) * 64;
#pragma unroll
            for (int i = 0; i < 4; ++i) {
                int chunk = wave * 4 + i;
                async16(aptr[i] + kk, &As[cur ^ 1][chunk * 512]);
                async16(bptr[i] + kk, &Bs[cur ^ 1][chunk * 512]);
            }
            asm volatile("s_waitcnt vmcnt(8)" ::: "memory");
        } else {
            asm volatile("s_waitcnt vmcnt(0)" ::: "memory");
        }
        __builtin_amdgcn_s_barrier();
#pragma unroll
        for (int kb = 0; kb < 2; ++kb) {
            const int goff = (((kb * 4 + quad) ^ l7)) * 8;
            bf16x8_t af[4], bfv[4];
#pragma unroll
            for (int i = 0; i < 4; ++i)
                af[i] = *(const bf16x8_t*)&As[cur][(wy * 64 + i * 16 + c16) * 64 + goff];
#pragma unroll
            for (int j = 0; j < 4; ++j)
                bfv[j] = *(const bf16x8_t*)&Bs[cur][(wx * 64 + j * 16 + c16) * 64 + goff];
#pragma unroll
            for (int i = 0; i < 4; ++i)
#pragma unroll
                for (int j = 0; j < 4; ++j)
                    acc[i][j] = __builtin_amdgcn_mfma_f32_16x16x32_bf16(
                        bfv[j], af[i], acc[i][j], 0, 0, 0);   // swapped: rows=N, cols=M
        }
        asm volatile("s_waitcnt lgkmcnt(0)" ::: "memory");
        __builtin_amdgcn_s_barrier();   // protect buf[cur] from next stage
    }

    // Swapped C/D layout: per (i,j) a lane holds cols colb..colb+3 of row
    // (m0 + wy*64 + i*16 + c16). Vectorized bf16x4 stores, float4 bias.
#pragma unroll
    for (int i = 0; i < 4; ++i) {
        const int row = m0 + wy * 64 + i * 16 + c16;
#pragma unroll
        for (int j = 0; j < 4; ++j) {
            const int colb = n0 + wx * 64 + j * 16 + quad * 4;
            float4 bv = *(const float4*)&bias[colb];
            bf16x4_t o;
            o[0] = (__bf16)(acc[i][j][0] + bv.x);
            o[1] = (__bf16)(acc[i][j][1] + bv.y);
            o[2] = (__bf16)(acc[i][j][2] + bv.z);
            o[3] = (__bf16)(acc[i][j][3] + bv.w);
            *(bf16x4_t*)&C[(size_t)row * 512 + colb] = o;
        }
    }
}

// ---------------------------------------------------------------------------
// Scores GEMM + softmax partials. A (L2-hot) double-buffered in LDS (depth-1
// prefetch covers ~250cyc L2 latency); B (embB, 41MB, L3/HBM-resident)
// TRIPLE-buffered (depth-2 covers ~600-900cyc). LDS = 2*16K + 3*16K = 80KB
// exactly -> 2 blocks/CU; redm/reds overlay onto As[0] (dead after K-loop).
// Counted vmcnt from FIFO queue: steady vmcnt(12) retires exactly A(t)+B(t).
// Swapped-operand epilogue (lane owns 16 values of one row) as r3/r4.
// ---------------------------------------------------------------------------
__global__ __launch_bounds__(256) void gemm_scores(
    const __bf16* __restrict__ A,      // 512 x 512 (gatheredB)
    const __bf16* __restrict__ Bm,     // 40064(pad) x 512 (embB)
    __bf16* __restrict__ scB,          // 512 x SCLD
    float* __restrict__ pmax, float* __restrict__ psum)
{
    const int bid = blockIdx.x;
    const int xcd = bid & 7, k = bid >> 3;       // k: 0..159
    const int nt = xcd * 40 + (k >> 2);
    if (nt >= NT) return;
    const int m0 = (k & 3) * 128, n0 = nt * 128;

    __shared__ __bf16 As[2][128 * 64];   // 32 KB
    __shared__ __bf16 Bs[3][128 * 64];   // 48 KB
    // overlay reduction scratch on As[0] (dead after the K-loop's last barrier)
    float* redm = (float*)&As[0][0];     // [2][128]
    float* reds = redm + 256;            // [2][128]

    const int tid = threadIdx.x, lane = tid & 63, wave = tid >> 6;
    const int wy = wave >> 1, wx = wave & 1;
    const int lrow = lane >> 3;
    const int lcol = (((lane & 7) ^ lrow) & 7) * 8;
    const int l7 = lane & 7, quad = lane >> 4, c16 = lane & 15;

    const __bf16* aptr[4]; const __bf16* bptr[4];
#pragma unroll
    for (int i = 0; i < 4; ++i) {
        int chunk = wave * 4 + i;
        aptr[i] = A + (size_t)(m0 + chunk * 8 + lrow) * 512 + lcol;
        bptr[i] = Bm + (size_t)(n0 + chunk * 8 + lrow) * 512 + lcol;
    }

    f32x4_t acc[4][4];
#pragma unroll
    for (int i = 0; i < 4; ++i)
#pragma unroll
        for (int j = 0; j < 4; ++j) acc[i][j] = (f32x4_t){0.f, 0.f, 0.f, 0.f};

    // prologue (issue order matters for vmcnt counting): A0, B0, B1
#pragma unroll
    for (int i = 0; i < 4; ++i)
        async16(aptr[i], &As[0][(wave * 4 + i) * 512]);
#pragma unroll
    for (int i = 0; i < 4; ++i)
        async16(bptr[i], &Bs[0][(wave * 4 + i) * 512]);
#pragma unroll
    for (int i = 0; i < 4; ++i)
        async16(bptr[i] + 64, &Bs[1][(wave * 4 + i) * 512]);

#pragma unroll
    for (int t = 0; t < 8; ++t) {
        const int cur = t & 1;        // As buffer
        const int bcur = t % 3;       // Bs buffer
        if (t < 7) {                  // stage A(t+1)
#pragma unroll
            for (int i = 0; i < 4; ++i)
                async16(aptr[i] + (t + 1) * 64, &As[cur ^ 1][(wave * 4 + i) * 512]);
        }
        if (t < 6) {                  // stage B(t+2)
#pragma unroll
            for (int i = 0; i < 4; ++i)
                async16(bptr[i] + (t + 2) * 64, &Bs[(t + 2) % 3][(wave * 4 + i) * 512]);
            // queue: [A(t),B(t) ... B(t+1), A(t+1), B(t+2)] -> retire A(t)+B(t)
            asm volatile("s_waitcnt vmcnt(12)" ::: "memory");
        } else if (t == 6) {
            asm volatile("s_waitcnt vmcnt(8)" ::: "memory");
        } else {
            asm volatile("s_waitcnt vmcnt(0)" ::: "memory");
        }
        __builtin_amdgcn_s_barrier();
#pragma unroll
        for (int kb = 0; kb < 2; ++kb) {
            const int goff = (((kb * 4 + quad) ^ l7)) * 8;
            bf16x8_t af[4], bfv[4];
#pragma unroll
            for (int i = 0; i < 4; ++i)
                af[i] = *(const bf16x8_t*)&As[cur][(wy * 64 + i * 16 + c16) * 64 + goff];
#pragma unroll
            for (int j = 0; j < 4; ++j)
                bfv[j] = *(const bf16x8_t*)&Bs[bcur][(wx * 64 + j * 16 + c16) * 64 + goff];
#pragma unroll
            for (int i = 0; i < 4; ++i)
#pragma unroll
                for (int j = 0; j < 4; ++j)
                    acc[i][j] = __builtin_amdgcn_mfma_f32_16x16x32_bf16(
                        bfv[j], af[i], acc[i][j], 0, 0, 0);   // swapped: rows=N, cols=M
        }
        asm volatile("s_waitcnt lgkmcnt(0)" ::: "memory");
        __builtin_amdgcn_s_barrier();   // protect buffers from later stages
    }

    // Epilogue: lane's 16 values all lie in row (m0+wy*64+i*16+c16);
    // cols n0+wx*64+j*16+quad*4 .. +3.  Lane-local softmax partials, then
    // cross-n lane combine (xor 16,32), then cross-wx combine via LDS.
    const bool tailb = (n0 + 128 > NCAND);
#pragma unroll
    for (int i = 0; i < 4; ++i) {
        const int lrw = wy * 64 + i * 16 + c16;       // tile-local row
        const size_t rowbase = (size_t)(m0 + lrw) * SCLD;
        float vs[4][4];
        float vmax = -FLT_MAX;
        float ssum = 0.f;
        if (!tailb) {
#pragma unroll
            for (int j = 0; j < 4; ++j) {
                const int nb = n0 + wx * 64 + j * 16 + quad * 4;
                bf16x4_t o;
#pragma unroll
                for (int rr = 0; rr < 4; ++rr) {
                    __bf16 xb = (__bf16)acc[i][j][rr];
                    o[rr] = xb;
                    float xr = (float)xb;
                    vs[j][rr] = xr;
                    vmax = fmaxf(vmax, xr);
                }
                *(bf16x4_t*)&scB[rowbase + nb] = o;
            }
#pragma unroll
            for (int j = 0; j < 4; ++j)
#pragma unroll
                for (int rr = 0; rr < 4; ++rr)
                    ssum += __expf(vs[j][rr] - vmax);
        } else {
            for (int j = 0; j < 4; ++j) {
                const int nb = n0 + wx * 64 + j * 16 + quad * 4;
                for (int rr = 0; rr < 4; ++rr) {
                    const int n = nb + rr;
                    __bf16 xb = (__bf16)acc[i][j][rr];
                    float xr = (float)xb;
                    if (n < NCAND) {
                        scB[rowbase + n] = xb;
                        vs[j][rr] = xr;
                        vmax = fmaxf(vmax, xr);
                    } else vs[j][rr] = -FLT_MAX;
                }
            }
            for (int j = 0; j < 4; ++j)
                for (int rr = 0; rr < 4; ++rr)
                    ssum += (vs[j][rr] > -FLT_MAX) ? __expf(vs[j][rr] - vmax) : 0.f;
        }
        // combine lanes {c16, c16+16, c16+32, c16+48} (same row, different n)
#pragma unroll
        for (int mk = 16; mk < 64; mk <<= 1) {
            float om = __shfl_xor(vmax, mk);
            float os = __shfl_xor(ssum, mk);
            float mm = fmaxf(vmax, om);
            ssum = ssum * __expf(vmax - mm) + os * __expf(om - mm);
            vmax = mm;
        }
        if (quad == 0) { redm[wx * 128 + lrw] = vmax; reds[wx * 128 + lrw] = ssum; }
    }
    __syncthreads();
    if (tid < 128) {
        float ma = redm[tid],       sa = reds[tid];
        float mb = redm[128 + tid], sb = reds[128 + tid];
        float mm = fmaxf(ma, mb);
        float ss = sa * __expf(ma - mm) + sb * __expf(mb - mm);
        pmax[(size_t)(m0 + tid) * NT + nt] = mm;     // [row][nt] layout
        psum[(size_t)(m0 + tid) * NT + nt] = ss;
    }
}

// ---------------------------------------------------------------------------
// Attention: one block per (b,h); K/V/Q head-slices staged in LDS once.
// 256 threads = 16 queries x 16 lanes. tanh fused at write.
// ---------------------------------------------------------------------------
#define KPAD 72
__global__ __launch_bounds__(256) void attn_kernel(const __bf16* __restrict__ Qg,
                                                   const __bf16* __restrict__ K,
                                                   const __bf16* __restrict__ V,
                                                   __bf16* __restrict__ attnB) {
    const int b = blockIdx.x, h = blockIdx.y, t = threadIdx.x;
    __shared__ __bf16 Ks[128 * KPAD];
    __shared__ __bf16 Vs[128 * KPAD];
    __shared__ float  Qs[16 * 68];
    __shared__ float  P[16 * 130];

    for (int i = t; i < 1024; i += 256) {
        int row = i >> 3, cg = (i & 7) * 8;
        size_t gsrc = ((size_t)(b * S_CURR + row)) * D + h * DH + cg;
        *(bf16x8_t*)&Ks[row * KPAD + cg] = *(const bf16x8_t*)&K[gsrc];
        *(bf16x8_t*)&Vs[row * KPAD + cg] = *(const bf16x8_t*)&V[gsrc];
    }
    if (t < 128) {
        int q = t >> 3, cg = (t & 7) * 8;
        bf16x8_t qv = *(const bf16x8_t*)&Qg[((size_t)(b * NM + q)) * D + h * DH + cg];
#pragma unroll
        for (int u = 0; u < 8; ++u) Qs[q * 68 + cg + u] = (float)qv[u];
    }
    __syncthreads();

    const int q = t >> 4, i = t & 15;
    float sv[8];
    float lmax = -FLT_MAX;
#pragma unroll
    for (int z = 0; z < 8; ++z) {
        int kk = i + z * 16;
        float s = 0.f;
#pragma unroll
        for (int d0 = 0; d0 < DH; d0 += 8) {
            bf16x8_t kv = *(const bf16x8_t*)&Ks[kk * KPAD + d0];
#pragma unroll
            for (int u = 0; u < 8; ++u) s += Qs[q * 68 + d0 + u] * (float)kv[u];
        }
        sv[z] = s; lmax = fmaxf(lmax, s);
    }
#pragma unroll
    for (int mk = 1; mk < 16; mk <<= 1) lmax = fmaxf(lmax, __shfl_xor(lmax, mk));
    float lsum = 0.f;
#pragma unroll
    for (int z = 0; z < 8; ++z) {
        float e = __expf(sv[z] - lmax);
        P[q * 130 + i + z * 16] = e;
        lsum += e;
    }
#pragma unroll
    for (int mk = 1; mk < 16; mk <<= 1) lsum += __shfl_xor(lsum, mk);
    const float inv = 1.0f / lsum;

    // P[q][*] produced and consumed by the same wave (q-group within wave) —
    // wave-order LDS semantics make this safe without a block barrier.
    const int d = i * 4;
    float a0 = 0.f, a1 = 0.f, a2 = 0.f, a3 = 0.f;
    for (int kk = 0; kk < 128; ++kk) {
        float p = P[q * 130 + kk];
        bf16x4_t vv = *(const bf16x4_t*)&Vs[kk * KPAD + d];
        a0 += p * (float)vv[0]; a1 += p * (float)vv[1];
        a2 += p * (float)vv[2]; a3 += p * (float)vv[3];
    }
    __bf16* o = attnB + ((size_t)(b * NM + q)) * D + h * DH + d;
    o[0] = (__bf16)tanhf(a0 * inv); o[1] = (__bf16)tanhf(a1 * inv);
    o[2] = (__bf16)tanhf(a2 * inv); o[3] = (__bf16)tanhf(a3 * inv);
}

// ---------------------------------------------------------------------------
__global__ __launch_bounds__(256) void lse_reduce(const float* __restrict__ pmax,
                                                  const float* __restrict__ psum,
                                                  float* __restrict__ lse) {
    int row = blockIdx.x, t = threadIdx.x;
    float m = -FLT_MAX, s = 0.f;
    for (int i = t; i < NT; i += 256) {
        float om = pmax[(size_t)row * NT + i];       // [row][nt]: coalesced
        float os = psum[(size_t)row * NT + i];
        float mm = fmaxf(m, om);
        s = s * __expf(m - mm) + os * __expf(om - mm);
        m = mm;
    }
    __shared__ float ms[256], ss[256];
    ms[t] = m; ss[t] = s;
    __syncthreads();
    for (int off = 128; off > 0; off >>= 1) {
        if (t < off) {
            float m1 = ms[t], s1 = ss[t], m2 = ms[t + off], s2 = ss[t + off];
            float mm = fmaxf(m1, m2);
            ms[t] = mm;
            ss[t] = s1 * __expf(m1 - mm) + s2 * __expf(m2 - mm);
        }
        __syncthreads();
    }
    if (t == 0) lse[row] = ms[0] + logf(ss[0]);
}

// ---------------------------------------------------------------------------
__global__ __launch_bounds__(256) void final_out(const __bf16* __restrict__ scB,
                                                 const float* __restrict__ lse,
                                                 float* __restrict__ out) {
    int row = blockIdx.y;
    int c0 = (blockIdx.x * 256 + threadIdx.x) * 8;
    if (c0 >= NCAND) return;
    float l = lse[row];
    bf16x8_t v = *(const bf16x8_t*)(scB + (size_t)row * SCLD + c0);
    float* o = out + (size_t)row * NCAND + c0;
    if (c0 + 8 <= NCAND) {
        *(float2*)(o)     = make_float2((float)v[0] - l, (float)v[1] - l);
        *(float2*)(o + 2) = make_float2((float)v[2] - l, (float)v[3] - l);
        *(float2*)(o + 4) = make_float2((float)v[4] - l, (float)v[5] - l);
        *(float2*)(o + 6) = make_float2((float)v[6] - l, (float)v[7] - l);
    } else {
        for (int k2 = 0; k2 < NCAND - c0; ++k2) o[k2] = (float)v[k2] - l;
    }
}

// ---------------------------------------------------------------------------
extern "C" void kernel_launch(void* const* d_in, const int* in_sizes, int n_in,
                              void* d_out, int out_size, void* d_ws, size_t ws_size,
                              hipStream_t stream) {
    const int*   mask_pos = (const int*)d_in[2];
    const int*   curr_idx = (const int*)d_in[3];
    const float* emb      = (const float*)d_in[5];
    const float* c_wq = (const float*)d_in[12];
    const float* c_bq = (const float*)d_in[13];
    const float* c_wk = (const float*)d_in[14];
    const float* c_bk = (const float*)d_in[15];
    const float* c_wv = (const float*)d_in[16];
    const float* c_bv = (const float*)d_in[17];
    const float* t2_w = (const float*)d_in[24];
    const float* t2_b = (const float*)d_in[25];
    float* out = (float*)d_out;

    char* w = (char*)d_ws;
    __bf16* embB  = (__bf16*)w;                           // 40064x512 bf16 = 41 MB
    __bf16* scB   = (__bf16*)(w + 41025536);              // 512x40064 bf16 = 41 MB
    __bf16* currB = scB;                                  // overlay (dead pre-scores)
    __bf16* Kf    = (__bf16*)(w + 41025536 + 4194304);
    __bf16* Vf    = (__bf16*)(w + 41025536 + 8388608);
    __bf16* Qg    = (__bf16*)(w + 41025536 + 12582912);
    __bf16* attnB = (__bf16*)(w + 41025536 + 13107200);
    __bf16* wqB   = (__bf16*)(w + 41025536 + 13631488);
    __bf16* wkB   = (__bf16*)(w + 41025536 + 14155776);
    __bf16* wvB   = (__bf16*)(w + 41025536 + 14680064);
    __bf16* t2wB  = (__bf16*)(w + 41025536 + 15204352);
    int*    qidx  = (int*)   (w + 41025536 + 15728640);
    __bf16* gatheredB = (__bf16*)(w + 82051072);
    float*  pmax  = (float*)(w + 82575360);
    float*  psum  = (float*)(w + 83216384);
    float*  lse   = (float*)(w + 83857408);

    hipLaunchKernelGGL(prep_kernel, dim3(14609), dim3(256), 0, stream,
                       emb, c_wq, c_wk, c_wv, t2_w, embB, wqB, wkB, wvB, t2wB,
                       curr_idx, currB, mask_pos, qidx);
    // K (z=0), V (z=1), Q-gathered (z=2, only 4 M-tiles) in one dispatch
    hipLaunchKernelGGL(gemm_bf, dim3(32, 4, 3), dim3(256), 0, stream,
                       currB, wkB, c_bk, Kf, wvB, c_bv, Vf, wqB, c_bq, Qg, qidx);
    hipLaunchKernelGGL(attn_kernel, dim3(B, H), dim3(256), 0, stream,
                       Qg, Kf, Vf, attnB);
    hipLaunchKernelGGL(gemm_bf, dim3(4, 4, 1), dim3(256), 0, stream,
                       attnB, t2wB, t2_b, gatheredB,
                       t2wB, t2_b, gatheredB, t2wB, t2_b, gatheredB,
                       (const int*)nullptr);
    hipLaunchKernelGGL(gemm_scores, dim3(1280), dim3(256), 0, stream,
                       gatheredB, embB, scB, pmax, psum);
    hipLaunchKernelGGL(lse_reduce, dim3(MG), dim3(256), 0, stream, pmax, psum, lse);
    hipLaunchKernelGGL(final_out, dim3(20, MG), dim3(256), 0, stream, scB, lse, out);
}

// Round 6
// 293.657 us; speedup vs baseline: 1.0350x; 1.0010x over previous
//
#include <hip/hip_runtime.h>
#include <hip/hip_bf16.h>
#include <math.h>
#include <float.h>

#define B       32
#define S_CURR  128
#define D       512
#define H       8
#define DH      64
#define NM      16
#define NCAND   39998          // emb[2:]
#define MG      (B * NM)       // 512 gathered rows
#define SCLD    40064          // padded row count of embB / col stride of scB
#define NT      313            // ceil(NCAND/128) N-tiles

typedef __bf16 bf16x8_t __attribute__((ext_vector_type(8)));
typedef __bf16 bf16x4_t __attribute__((ext_vector_type(4)));
typedef __bf16 bf16x2_t __attribute__((ext_vector_type(2)));
typedef float  f32x4_t  __attribute__((ext_vector_type(4)));

typedef __attribute__((address_space(3))) unsigned int lds_u32_t;
typedef const __attribute__((address_space(1))) unsigned int gbl_u32_t;

__device__ __forceinline__ void async16(const void* g, void* l) {
    __builtin_amdgcn_global_load_lds((gbl_u32_t*)g, (lds_u32_t*)l, 16, 0, 0);
}

// ---------------------------------------------------------------------------
// Prep kernel: bx < 10512 -> f32->bf16 converts (emb[2:], 4 weight mats);
// 10512 <= bx < 14608 -> currB = bf16(emb[idx]+pe); bx == 14608 -> qidx.
// Fast-math trig (__expf/__sinf/__cosf): tolerance 0.5, bf16 rounding dwarfs
// intrinsic error.
// ---------------------------------------------------------------------------
__global__ __launch_bounds__(256) void prep_kernel(
    const float* __restrict__ emb,
    const float* __restrict__ wq, const float* __restrict__ wk,
    const float* __restrict__ wv, const float* __restrict__ t2w,
    __bf16* __restrict__ embB, __bf16* __restrict__ wqB, __bf16* __restrict__ wkB,
    __bf16* __restrict__ wvB, __bf16* __restrict__ t2wB,
    const int* __restrict__ curr_idx, __bf16* __restrict__ currB,
    const int* __restrict__ mask_pos, int* __restrict__ qidx)
{
    int bx = blockIdx.x;
    if (bx < 10512) {
        const float* src; __bf16* dst; size_t n, base;
        if (bx < 10000) {
            src = emb + 2 * D; dst = embB; n = (size_t)NCAND * D; base = (size_t)bx * 2048;
        } else {
            int w = (bx - 10000) >> 7;
            base = (size_t)((bx - 10000) & 127) * 2048;
            n = (size_t)D * D;
            src = (w == 0) ? wq : (w == 1) ? wk : (w == 2) ? wv : t2w;
            dst = (w == 0) ? wqB : (w == 1) ? wkB : (w == 2) ? wvB : t2wB;
        }
        size_t i = base + (size_t)threadIdx.x * 8;
        if (i >= n) return;
        float4 a = *(const float4*)(src + i);
        float4 b = *(const float4*)(src + i + 4);
        bf16x8_t v;
        v[0] = (__bf16)a.x; v[1] = (__bf16)a.y; v[2] = (__bf16)a.z; v[3] = (__bf16)a.w;
        v[4] = (__bf16)b.x; v[5] = (__bf16)b.y; v[6] = (__bf16)b.z; v[7] = (__bf16)b.w;
        *(bf16x8_t*)(dst + i) = v;
        return;
    }
    if (bx == 14608) {
        int r = threadIdx.x;
        qidx[r] = (r >> 4) * S_CURR + mask_pos[r];
        r += 256;
        qidx[r] = (r >> 4) * S_CURR + mask_pos[r];
        return;
    }
    int bs = bx - 10512;
    int s = bs & (S_CURR - 1);
    int g = curr_idx[bs];
    const float* e = emb + (size_t)g * D;
    __bf16* o = currB + (size_t)bs * D;
    int d = threadIdx.x * 2;
    float div = __expf(-(float)d * (9.210340371976184f / 512.0f));
    float ang = (float)s * div;
    float2 ev = *(const float2*)(e + d);
    bf16x2_t ov;
    ov[0] = (__bf16)(ev.x + __sinf(ang));
    ov[1] = (__bf16)(ev.y + __cosf(ang));
    *(bf16x2_t*)(o + d) = ov;
}

// ---------------------------------------------------------------------------
// bf16 GEMM, swizzled-LDS, double-buffered counted-vmcnt prefetch.
// C = A @ W^T + bias, K=512, N=512.
// SWAPPED-OPERAND MFMA: mfma(bfv, af) puts the N index on the register axis
// (lane owns 4 consecutive output cols at one row) -> bf16x4 vectorized C
// stores + float4 bias loads. Fragment staging/loads unchanged.
// ---------------------------------------------------------------------------
__global__ __launch_bounds__(256) void gemm_bf(
    const __bf16* __restrict__ A,
    const __bf16* __restrict__ W0, const float* __restrict__ b0, __bf16* __restrict__ C0,
    const __bf16* __restrict__ W1, const float* __restrict__ b1, __bf16* __restrict__ C1,
    const __bf16* __restrict__ W2, const float* __restrict__ b2, __bf16* __restrict__ C2,
    const int* __restrict__ rowidx)
{
    const int z = blockIdx.z;
    if (z == 2 && blockIdx.x >= 4) return;   // Q problem has M=512 only
    const __bf16* W = (z == 0) ? W0 : (z == 1) ? W1 : W2;
    const float* bias = (z == 0) ? b0 : (z == 1) ? b1 : b2;
    __bf16* C = (z == 0) ? C0 : (z == 1) ? C1 : C2;

    __shared__ __bf16 As[2][128 * 64];
    __shared__ __bf16 Bs[2][128 * 64];

    const int tid = threadIdx.x, lane = tid & 63, wave = tid >> 6;
    const int wy = wave >> 1, wx = wave & 1;
    const int m0 = blockIdx.x * 128, n0 = blockIdx.y * 128;
    const int lrow = lane >> 3;
    const int lcol = (((lane & 7) ^ lrow) & 7) * 8;   // swizzled source column

    const __bf16* aptr[4]; const __bf16* bptr[4];
#pragma unroll
    for (int i = 0; i < 4; ++i) {
        int chunk = wave * 4 + i;
        int ar = m0 + chunk * 8 + lrow;
        if (z == 2) ar = rowidx[ar];
        aptr[i] = A + (size_t)ar * 512 + lcol;
        bptr[i] = W + (size_t)(n0 + chunk * 8 + lrow) * 512 + lcol;
    }

    f32x4_t acc[4][4];
#pragma unroll
    for (int i = 0; i < 4; ++i)
#pragma unroll
        for (int j = 0; j < 4; ++j) acc[i][j] = (f32x4_t){0.f, 0.f, 0.f, 0.f};

    const int l7 = lane & 7, quad = lane >> 4, c16 = lane & 15;

    // prologue: stage K-step 0 into buffer 0
#pragma unroll
    for (int i = 0; i < 4; ++i) {
        int chunk = wave * 4 + i;
        async16(aptr[i], &As[0][chunk * 512]);
        async16(bptr[i], &Bs[0][chunk * 512]);
    }

#pragma unroll
    for (int t = 0; t < 8; ++t) {
        const int cur = t & 1;
        if (t < 7) {
            const int kk = (t + 1) * 64;
#pragma unroll
            for (int i = 0; i < 4; ++i) {
                int chunk = wave * 4 + i;
                async16(aptr[i] + kk, &As[cur ^ 1][chunk * 512]);
                async16(bptr[i] + kk, &Bs[cur ^ 1][chunk * 512]);
            }
            asm volatile("s_waitcnt vmcnt(8)" ::: "memory");
        } else {
            asm volatile("s_waitcnt vmcnt(0)" ::: "memory");
        }
        __builtin_amdgcn_s_barrier();
#pragma unroll
        for (int kb = 0; kb < 2; ++kb) {
            const int goff = (((kb * 4 + quad) ^ l7)) * 8;
            bf16x8_t af[4], bfv[4];
#pragma unroll
            for (int i = 0; i < 4; ++i)
                af[i] = *(const bf16x8_t*)&As[cur][(wy * 64 + i * 16 + c16) * 64 + goff];
#pragma unroll
            for (int j = 0; j < 4; ++j)
                bfv[j] = *(const bf16x8_t*)&Bs[cur][(wx * 64 + j * 16 + c16) * 64 + goff];
#pragma unroll
            for (int i = 0; i < 4; ++i)
#pragma unroll
                for (int j = 0; j < 4; ++j)
                    acc[i][j] = __builtin_amdgcn_mfma_f32_16x16x32_bf16(
                        bfv[j], af[i], acc[i][j], 0, 0, 0);   // swapped: rows=N, cols=M
        }
        asm volatile("s_waitcnt lgkmcnt(0)" ::: "memory");
        __builtin_amdgcn_s_barrier();   // protect buf[cur] from next stage
    }

    // Swapped C/D layout: per (i,j) a lane holds cols colb..colb+3 of row
    // (m0 + wy*64 + i*16 + c16). Vectorized bf16x4 stores, float4 bias.
#pragma unroll
    for (int i = 0; i < 4; ++i) {
        const int row = m0 + wy * 64 + i * 16 + c16;
#pragma unroll
        for (int j = 0; j < 4; ++j) {
            const int colb = n0 + wx * 64 + j * 16 + quad * 4;
            float4 bv = *(const float4*)&bias[colb];
            bf16x4_t o;
            o[0] = (__bf16)(acc[i][j][0] + bv.x);
            o[1] = (__bf16)(acc[i][j][1] + bv.y);
            o[2] = (__bf16)(acc[i][j][2] + bv.z);
            o[3] = (__bf16)(acc[i][j][3] + bv.w);
            *(bf16x4_t*)&C[(size_t)row * 512 + colb] = o;
        }
    }
}

// ---------------------------------------------------------------------------
// Scores GEMM + softmax partials — the measured-best r3 configuration:
// A+B double-buffered LDS (66KB), depth-1 counted vmcnt(8), swapped-operand
// epilogue (lane owns 16 values of one row), pmax/psum in [row][nt] layout.
// ---------------------------------------------------------------------------
__global__ __launch_bounds__(256) void gemm_scores(
    const __bf16* __restrict__ A,      // 512 x 512 (gatheredB)
    const __bf16* __restrict__ Bm,     // 40064(pad) x 512 (embB)
    __bf16* __restrict__ scB,          // 512 x SCLD
    float* __restrict__ pmax, float* __restrict__ psum)
{
    const int bid = blockIdx.x;
    const int xcd = bid & 7, k = bid >> 3;       // k: 0..159
    const int nt = xcd * 40 + (k >> 2);
    if (nt >= NT) return;
    const int m0 = (k & 3) * 128, n0 = nt * 128;

    __shared__ __bf16 As[2][128 * 64];
    __shared__ __bf16 Bs[2][128 * 64];
    __shared__ float redm[2][128], reds[2][128];

    const int tid = threadIdx.x, lane = tid & 63, wave = tid >> 6;
    const int wy = wave >> 1, wx = wave & 1;
    const int lrow = lane >> 3;
    const int lcol = (((lane & 7) ^ lrow) & 7) * 8;

    const __bf16* aptr[4]; const __bf16* bptr[4];
#pragma unroll
    for (int i = 0; i < 4; ++i) {
        int chunk = wave * 4 + i;
        aptr[i] = A + (size_t)(m0 + chunk * 8 + lrow) * 512 + lcol;
        bptr[i] = Bm + (size_t)(n0 + chunk * 8 + lrow) * 512 + lcol;
    }

    f32x4_t acc[4][4];
#pragma unroll
    for (int i = 0; i < 4; ++i)
#pragma unroll
        for (int j = 0; j < 4; ++j) acc[i][j] = (f32x4_t){0.f, 0.f, 0.f, 0.f};

    const int l7 = lane & 7, quad = lane >> 4, c16 = lane & 15;

    // prologue: stage K-step 0 into buffer 0
#pragma unroll
    for (int i = 0; i < 4; ++i) {
        int chunk = wave * 4 + i;
        async16(aptr[i], &As[0][chunk * 512]);
        async16(bptr[i], &Bs[0][chunk * 512]);
    }

#pragma unroll
    for (int t = 0; t < 8; ++t) {
        const int cur = t & 1;
        if (t < 7) {
            const int kk = (t + 1) * 64;
#pragma unroll
            for (int i = 0; i < 4; ++i) {
                int chunk = wave * 4 + i;
                async16(aptr[i] + kk, &As[cur ^ 1][chunk * 512]);
                async16(bptr[i] + kk, &Bs[cur ^ 1][chunk * 512]);
            }
            asm volatile("s_waitcnt vmcnt(8)" ::: "memory");
        } else {
            asm volatile("s_waitcnt vmcnt(0)" ::: "memory");
        }
        __builtin_amdgcn_s_barrier();
#pragma unroll
        for (int kb = 0; kb < 2; ++kb) {
            const int goff = (((kb * 4 + quad) ^ l7)) * 8;
            bf16x8_t af[4], bfv[4];
#pragma unroll
            for (int i = 0; i < 4; ++i)
                af[i] = *(const bf16x8_t*)&As[cur][(wy * 64 + i * 16 + c16) * 64 + goff];
#pragma unroll
            for (int j = 0; j < 4; ++j)
                bfv[j] = *(const bf16x8_t*)&Bs[cur][(wx * 64 + j * 16 + c16) * 64 + goff];
#pragma unroll
            for (int i = 0; i < 4; ++i)
#pragma unroll
                for (int j = 0; j < 4; ++j)
                    acc[i][j] = __builtin_amdgcn_mfma_f32_16x16x32_bf16(
                        bfv[j], af[i], acc[i][j], 0, 0, 0);   // swapped: rows=N, cols=M
        }
        asm volatile("s_waitcnt lgkmcnt(0)" ::: "memory");
        __builtin_amdgcn_s_barrier();   // protect buf[cur] from next stage
    }

    // Epilogue: lane's 16 values all lie in row (m0+wy*64+i*16+c16);
    // cols n0+wx*64+j*16+quad*4 .. +3.  Lane-local softmax partials, then
    // cross-n lane combine (xor 16,32), then cross-wx combine via LDS.
    const bool tailb = (n0 + 128 > NCAND);
#pragma unroll
    for (int i = 0; i < 4; ++i) {
        const int lrw = wy * 64 + i * 16 + c16;       // tile-local row
        const size_t rowbase = (size_t)(m0 + lrw) * SCLD;
        float vs[4][4];
        float vmax = -FLT_MAX;
        float ssum = 0.f;
        if (!tailb) {
#pragma unroll
            for (int j = 0; j < 4; ++j) {
                const int nb = n0 + wx * 64 + j * 16 + quad * 4;
                bf16x4_t o;
#pragma unroll
                for (int rr = 0; rr < 4; ++rr) {
                    __bf16 xb = (__bf16)acc[i][j][rr];
                    o[rr] = xb;
                    float xr = (float)xb;
                    vs[j][rr] = xr;
                    vmax = fmaxf(vmax, xr);
                }
                *(bf16x4_t*)&scB[rowbase + nb] = o;
            }
#pragma unroll
            for (int j = 0; j < 4; ++j)
#pragma unroll
                for (int rr = 0; rr < 4; ++rr)
                    ssum += __expf(vs[j][rr] - vmax);
        } else {
            for (int j = 0; j < 4; ++j) {
                const int nb = n0 + wx * 64 + j * 16 + quad * 4;
                for (int rr = 0; rr < 4; ++rr) {
                    const int n = nb + rr;
                    __bf16 xb = (__bf16)acc[i][j][rr];
                    float xr = (float)xb;
                    if (n < NCAND) {
                        scB[rowbase + n] = xb;
                        vs[j][rr] = xr;
                        vmax = fmaxf(vmax, xr);
                    } else vs[j][rr] = -FLT_MAX;
                }
            }
            for (int j = 0; j < 4; ++j)
                for (int rr = 0; rr < 4; ++rr)
                    ssum += (vs[j][rr] > -FLT_MAX) ? __expf(vs[j][rr] - vmax) : 0.f;
        }
        // combine lanes {c16, c16+16, c16+32, c16+48} (same row, different n)
#pragma unroll
        for (int mk = 16; mk < 64; mk <<= 1) {
            float om = __shfl_xor(vmax, mk);
            float os = __shfl_xor(ssum, mk);
            float mm = fmaxf(vmax, om);
            ssum = ssum * __expf(vmax - mm) + os * __expf(om - mm);
            vmax = mm;
        }
        if (quad == 0) { redm[wx][lrw] = vmax; reds[wx][lrw] = ssum; }
    }
    __syncthreads();
    if (tid < 128) {
        float ma = redm[0][tid], sa = reds[0][tid];
        float mb = redm[1][tid], sb = reds[1][tid];
        float mm = fmaxf(ma, mb);
        float ss = sa * __expf(ma - mm) + sb * __expf(mb - mm);
        pmax[(size_t)(m0 + tid) * NT + nt] = mm;     // [row][nt] layout
        psum[(size_t)(m0 + tid) * NT + nt] = ss;
    }
}

// ---------------------------------------------------------------------------
// Attention: one block per (b,h); K/V/Q head-slices staged in LDS once.
// 256 threads = 16 queries x 16 lanes. tanh fused at write.
// ---------------------------------------------------------------------------
#define KPAD 72
__global__ __launch_bounds__(256) void attn_kernel(const __bf16* __restrict__ Qg,
                                                   const __bf16* __restrict__ K,
                                                   const __bf16* __restrict__ V,
                                                   __bf16* __restrict__ attnB) {
    const int b = blockIdx.x, h = blockIdx.y, t = threadIdx.x;
    __shared__ __bf16 Ks[128 * KPAD];
    __shared__ __bf16 Vs[128 * KPAD];
    __shared__ float  Qs[16 * 68];
    __shared__ float  P[16 * 130];

    for (int i = t; i < 1024; i += 256) {
        int row = i >> 3, cg = (i & 7) * 8;
        size_t gsrc = ((size_t)(b * S_CURR + row)) * D + h * DH + cg;
        *(bf16x8_t*)&Ks[row * KPAD + cg] = *(const bf16x8_t*)&K[gsrc];
        *(bf16x8_t*)&Vs[row * KPAD + cg] = *(const bf16x8_t*)&V[gsrc];
    }
    if (t < 128) {
        int q = t >> 3, cg = (t & 7) * 8;
        bf16x8_t qv = *(const bf16x8_t*)&Qg[((size_t)(b * NM + q)) * D + h * DH + cg];
#pragma unroll
        for (int u = 0; u < 8; ++u) Qs[q * 68 + cg + u] = (float)qv[u];
    }
    __syncthreads();

    const int q = t >> 4, i = t & 15;
    float sv[8];
    float lmax = -FLT_MAX;
#pragma unroll
    for (int z = 0; z < 8; ++z) {
        int kk = i + z * 16;
        float s = 0.f;
#pragma unroll
        for (int d0 = 0; d0 < DH; d0 += 8) {
            bf16x8_t kv = *(const bf16x8_t*)&Ks[kk * KPAD + d0];
#pragma unroll
            for (int u = 0; u < 8; ++u) s += Qs[q * 68 + d0 + u] * (float)kv[u];
        }
        sv[z] = s; lmax = fmaxf(lmax, s);
    }
#pragma unroll
    for (int mk = 1; mk < 16; mk <<= 1) lmax = fmaxf(lmax, __shfl_xor(lmax, mk));
    float lsum = 0.f;
#pragma unroll
    for (int z = 0; z < 8; ++z) {
        float e = __expf(sv[z] - lmax);
        P[q * 130 + i + z * 16] = e;
        lsum += e;
    }
#pragma unroll
    for (int mk = 1; mk < 16; mk <<= 1) lsum += __shfl_xor(lsum, mk);
    const float inv = 1.0f / lsum;

    // P[q][*] produced and consumed by the same wave (q-group within wave) —
    // wave-order LDS semantics make this safe without a block barrier.
    const int d = i * 4;
    float a0 = 0.f, a1 = 0.f, a2 = 0.f, a3 = 0.f;
    for (int kk = 0; kk < 128; ++kk) {
        float p = P[q * 130 + kk];
        bf16x4_t vv = *(const bf16x4_t*)&Vs[kk * KPAD + d];
        a0 += p * (float)vv[0]; a1 += p * (float)vv[1];
        a2 += p * (float)vv[2]; a3 += p * (float)vv[3];
    }
    __bf16* o = attnB + ((size_t)(b * NM + q)) * D + h * DH + d;
    o[0] = (__bf16)tanhf(a0 * inv); o[1] = (__bf16)tanhf(a1 * inv);
    o[2] = (__bf16)tanhf(a2 * inv); o[3] = (__bf16)tanhf(a3 * inv);
}

// ---------------------------------------------------------------------------
// Fused LSE + final output: one block per gathered row. Phase 1 reduces the
// row's 313 (pmax,psum) partials ([row][nt] layout -> coalesced); phase 2
// streams the row: out = f32(scB) - lse. Replaces lse_reduce + final_out.
// ---------------------------------------------------------------------------
__global__ __launch_bounds__(256) void lse_final(const float* __restrict__ pmax,
                                                 const float* __restrict__ psum,
                                                 const __bf16* __restrict__ scB,
                                                 float* __restrict__ out) {
    const int row = blockIdx.x, t = threadIdx.x;
    __shared__ float ms[256], ss[256];
    float m = -FLT_MAX, s = 0.f;
    for (int i = t; i < NT; i += 256) {
        float om = pmax[(size_t)row * NT + i];
        float os = psum[(size_t)row * NT + i];
        float mm = fmaxf(m, om);
        s = s * __expf(m - mm) + os * __expf(om - mm);
        m = mm;
    }
    ms[t] = m; ss[t] = s;
    __syncthreads();
    for (int off = 128; off > 0; off >>= 1) {
        if (t < off) {
            float m1 = ms[t], s1 = ss[t], m2 = ms[t + off], s2 = ss[t + off];
            float mm = fmaxf(m1, m2);
            ms[t] = mm;
            ss[t] = s1 * __expf(m1 - mm) + s2 * __expf(m2 - mm);
        }
        __syncthreads();
    }
    const float l = ms[0] + logf(ss[0]);

    const __bf16* src = scB + (size_t)row * SCLD;
    float* o = out + (size_t)row * NCAND;
    for (int c0 = t * 8; c0 < NCAND; c0 += 256 * 8) {
        bf16x8_t v = *(const bf16x8_t*)(src + c0);   // SCLD pad keeps tail read in-bounds
        if (c0 + 8 <= NCAND) {
            *(float2*)(o + c0)     = make_float2((float)v[0] - l, (float)v[1] - l);
            *(float2*)(o + c0 + 2) = make_float2((float)v[2] - l, (float)v[3] - l);
            *(float2*)(o + c0 + 4) = make_float2((float)v[4] - l, (float)v[5] - l);
            *(float2*)(o + c0 + 6) = make_float2((float)v[6] - l, (float)v[7] - l);
        } else {
            for (int k2 = 0; k2 < NCAND - c0; ++k2) o[c0 + k2] = (float)v[k2] - l;
        }
    }
}

// ---------------------------------------------------------------------------
extern "C" void kernel_launch(void* const* d_in, const int* in_sizes, int n_in,
                              void* d_out, int out_size, void* d_ws, size_t ws_size,
                              hipStream_t stream) {
    const int*   mask_pos = (const int*)d_in[2];
    const int*   curr_idx = (const int*)d_in[3];
    const float* emb      = (const float*)d_in[5];
    const float* c_wq = (const float*)d_in[12];
    const float* c_bq = (const float*)d_in[13];
    const float* c_wk = (const float*)d_in[14];
    const float* c_bk = (const float*)d_in[15];
    const float* c_wv = (const float*)d_in[16];
    const float* c_bv = (const float*)d_in[17];
    const float* t2_w = (const float*)d_in[24];
    const float* t2_b = (const float*)d_in[25];
    float* out = (float*)d_out;

    char* w = (char*)d_ws;
    __bf16* embB  = (__bf16*)w;                           // 40064x512 bf16 = 41 MB
    __bf16* scB   = (__bf16*)(w + 41025536);              // 512x40064 bf16 = 41 MB
    __bf16* currB = scB;                                  // overlay (dead pre-scores)
    __bf16* Kf    = (__bf16*)(w + 41025536 + 4194304);
    __bf16* Vf    = (__bf16*)(w + 41025536 + 8388608);
    __bf16* Qg    = (__bf16*)(w + 41025536 + 12582912);
    __bf16* attnB = (__bf16*)(w + 41025536 + 13107200);
    __bf16* wqB   = (__bf16*)(w + 41025536 + 13631488);
    __bf16* wkB   = (__bf16*)(w + 41025536 + 14155776);
    __bf16* wvB   = (__bf16*)(w + 41025536 + 14680064);
    __bf16* t2wB  = (__bf16*)(w + 41025536 + 15204352);
    int*    qidx  = (int*)   (w + 41025536 + 15728640);
    __bf16* gatheredB = (__bf16*)(w + 82051072);
    float*  pmax  = (float*)(w + 82575360);
    float*  psum  = (float*)(w + 83216384);

    hipLaunchKernelGGL(prep_kernel, dim3(14609), dim3(256), 0, stream,
                       emb, c_wq, c_wk, c_wv, t2_w, embB, wqB, wkB, wvB, t2wB,
                       curr_idx, currB, mask_pos, qidx);
    // K (z=0), V (z=1), Q-gathered (z=2, only 4 M-tiles) in one dispatch
    hipLaunchKernelGGL(gemm_bf, dim3(32, 4, 3), dim3(256), 0, stream,
                       currB, wkB, c_bk, Kf, wvB, c_bv, Vf, wqB, c_bq, Qg, qidx);
    hipLaunchKernelGGL(attn_kernel, dim3(B, H), dim3(256), 0, stream,
                       Qg, Kf, Vf, attnB);
    hipLaunchKernelGGL(gemm_bf, dim3(4, 4, 1), dim3(256), 0, stream,
                       attnB, t2wB, t2_b, gatheredB,
                       t2wB, t2_b, gatheredB, t2wB, t2_b, gatheredB,
                       (const int*)nullptr);
    hipLaunchKernelGGL(gemm_scores, dim3(1280), dim3(256), 0, stream,
                       gatheredB, embB, scB, pmax, psum);
    hipLaunchKernelGGL(lse_final, dim3(MG), dim3(256), 0, stream,
                       pmax, psum, scB, out);
}

// Round 7
// 289.682 us; speedup vs baseline: 1.0492x; 1.0137x over previous
//
#include <hip/hip_runtime.h>
#include <hip/hip_bf16.h>
#include <math.h>
#include <float.h>

#define B       32
#define S_CURR  128
#define D       512
#define H       8
#define DH      64
#define NM      16
#define NCAND   39998          // emb[2:]
#define MG      (B * NM)       // 512 gathered rows
#define SCLD    40064          // padded row count of embB / col stride of scB
#define NT      313            // ceil(NCAND/128) N-tiles

typedef __bf16 bf16x8_t __attribute__((ext_vector_type(8)));
typedef __bf16 bf16x4_t __attribute__((ext_vector_type(4)));
typedef __bf16 bf16x2_t __attribute__((ext_vector_type(2)));
typedef float  f32x4_t  __attribute__((ext_vector_type(4)));

typedef __attribute__((address_space(3))) unsigned int lds_u32_t;
typedef const __attribute__((address_space(1))) unsigned int gbl_u32_t;

__device__ __forceinline__ void async16(const void* g, void* l) {
    __builtin_amdgcn_global_load_lds((gbl_u32_t*)g, (lds_u32_t*)l, 16, 0, 0);
}

// ---------------------------------------------------------------------------
// Prep kernel: bx < 10512 -> f32->bf16 converts (emb[2:], 4 weight mats);
// 10512 <= bx < 14608 -> currB = bf16(emb[idx]+pe); bx == 14608 -> qidx.
// ---------------------------------------------------------------------------
__global__ __launch_bounds__(256) void prep_kernel(
    const float* __restrict__ emb,
    const float* __restrict__ wq, const float* __restrict__ wk,
    const float* __restrict__ wv, const float* __restrict__ t2w,
    __bf16* __restrict__ embB, __bf16* __restrict__ wqB, __bf16* __restrict__ wkB,
    __bf16* __restrict__ wvB, __bf16* __restrict__ t2wB,
    const int* __restrict__ curr_idx, __bf16* __restrict__ currB,
    const int* __restrict__ mask_pos, int* __restrict__ qidx)
{
    int bx = blockIdx.x;
    if (bx < 10512) {
        const float* src; __bf16* dst; size_t n, base;
        if (bx < 10000) {
            src = emb + 2 * D; dst = embB; n = (size_t)NCAND * D; base = (size_t)bx * 2048;
        } else {
            int w = (bx - 10000) >> 7;
            base = (size_t)((bx - 10000) & 127) * 2048;
            n = (size_t)D * D;
            src = (w == 0) ? wq : (w == 1) ? wk : (w == 2) ? wv : t2w;
            dst = (w == 0) ? wqB : (w == 1) ? wkB : (w == 2) ? wvB : t2wB;
        }
        size_t i = base + (size_t)threadIdx.x * 8;
        if (i >= n) return;
        float4 a = *(const float4*)(src + i);
        float4 b = *(const float4*)(src + i + 4);
        bf16x8_t v;
        v[0] = (__bf16)a.x; v[1] = (__bf16)a.y; v[2] = (__bf16)a.z; v[3] = (__bf16)a.w;
        v[4] = (__bf16)b.x; v[5] = (__bf16)b.y; v[6] = (__bf16)b.z; v[7] = (__bf16)b.w;
        *(bf16x8_t*)(dst + i) = v;
        return;
    }
    if (bx == 14608) {
        int r = threadIdx.x;
        qidx[r] = (r >> 4) * S_CURR + mask_pos[r];
        r += 256;
        qidx[r] = (r >> 4) * S_CURR + mask_pos[r];
        return;
    }
    int bs = bx - 10512;
    int s = bs & (S_CURR - 1);
    int g = curr_idx[bs];
    const float* e = emb + (size_t)g * D;
    __bf16* o = currB + (size_t)bs * D;
    int d = threadIdx.x * 2;
    float div = __expf(-(float)d * (9.210340371976184f / 512.0f));
    float ang = (float)s * div;
    float2 ev = *(const float2*)(e + d);
    bf16x2_t ov;
    ov[0] = (__bf16)(ev.x + __sinf(ang));
    ov[1] = (__bf16)(ev.y + __cosf(ang));
    *(bf16x2_t*)(o + d) = ov;
}

// ---------------------------------------------------------------------------
// bf16 GEMM, swizzled-LDS, double-buffered counted-vmcnt prefetch.
// C = A @ W^T + bias, K=512, N=512. Unchanged from r6 (measured-good).
// ---------------------------------------------------------------------------
__global__ __launch_bounds__(256) void gemm_bf(
    const __bf16* __restrict__ A,
    const __bf16* __restrict__ W0, const float* __restrict__ b0, __bf16* __restrict__ C0,
    const __bf16* __restrict__ W1, const float* __restrict__ b1, __bf16* __restrict__ C1,
    const __bf16* __restrict__ W2, const float* __restrict__ b2, __bf16* __restrict__ C2,
    const int* __restrict__ rowidx)
{
    const int z = blockIdx.z;
    if (z == 2 && blockIdx.x >= 4) return;   // Q problem has M=512 only
    const __bf16* W = (z == 0) ? W0 : (z == 1) ? W1 : W2;
    const float* bias = (z == 0) ? b0 : (z == 1) ? b1 : b2;
    __bf16* C = (z == 0) ? C0 : (z == 1) ? C1 : C2;

    __shared__ __bf16 As[2][128 * 64];
    __shared__ __bf16 Bs[2][128 * 64];

    const int tid = threadIdx.x, lane = tid & 63, wave = tid >> 6;
    const int wy = wave >> 1, wx = wave & 1;
    const int m0 = blockIdx.x * 128, n0 = blockIdx.y * 128;
    const int lrow = lane >> 3;
    const int lcol = (((lane & 7) ^ lrow) & 7) * 8;   // swizzled source column

    const __bf16* aptr[4]; const __bf16* bptr[4];
#pragma unroll
    for (int i = 0; i < 4; ++i) {
        int chunk = wave * 4 + i;
        int ar = m0 + chunk * 8 + lrow;
        if (z == 2) ar = rowidx[ar];
        aptr[i] = A + (size_t)ar * 512 + lcol;
        bptr[i] = W + (size_t)(n0 + chunk * 8 + lrow) * 512 + lcol;
    }

    f32x4_t acc[4][4];
#pragma unroll
    for (int i = 0; i < 4; ++i)
#pragma unroll
        for (int j = 0; j < 4; ++j) acc[i][j] = (f32x4_t){0.f, 0.f, 0.f, 0.f};

    const int l7 = lane & 7, quad = lane >> 4, c16 = lane & 15;

    // prologue: stage K-step 0 into buffer 0
#pragma unroll
    for (int i = 0; i < 4; ++i) {
        int chunk = wave * 4 + i;
        async16(aptr[i], &As[0][chunk * 512]);
        async16(bptr[i], &Bs[0][chunk * 512]);
    }

#pragma unroll
    for (int t = 0; t < 8; ++t) {
        const int cur = t & 1;
        if (t < 7) {
            const int kk = (t + 1) * 64;
#pragma unroll
            for (int i = 0; i < 4; ++i) {
                int chunk = wave * 4 + i;
                async16(aptr[i] + kk, &As[cur ^ 1][chunk * 512]);
                async16(bptr[i] + kk, &Bs[cur ^ 1][chunk * 512]);
            }
            asm volatile("s_waitcnt vmcnt(8)" ::: "memory");
        } else {
            asm volatile("s_waitcnt vmcnt(0)" ::: "memory");
        }
        __builtin_amdgcn_s_barrier();
#pragma unroll
        for (int kb = 0; kb < 2; ++kb) {
            const int goff = (((kb * 4 + quad) ^ l7)) * 8;
            bf16x8_t af[4], bfv[4];
#pragma unroll
            for (int i = 0; i < 4; ++i)
                af[i] = *(const bf16x8_t*)&As[cur][(wy * 64 + i * 16 + c16) * 64 + goff];
#pragma unroll
            for (int j = 0; j < 4; ++j)
                bfv[j] = *(const bf16x8_t*)&Bs[cur][(wx * 64 + j * 16 + c16) * 64 + goff];
#pragma unroll
            for (int i = 0; i < 4; ++i)
#pragma unroll
                for (int j = 0; j < 4; ++j)
                    acc[i][j] = __builtin_amdgcn_mfma_f32_16x16x32_bf16(
                        bfv[j], af[i], acc[i][j], 0, 0, 0);   // swapped: rows=N, cols=M
        }
        asm volatile("s_waitcnt lgkmcnt(0)" ::: "memory");
        __builtin_amdgcn_s_barrier();   // protect buf[cur] from next stage
    }

    // Swapped C/D layout: per (i,j) a lane holds cols colb..colb+3 of row
    // (m0 + wy*64 + i*16 + c16). Vectorized bf16x4 stores, float4 bias.
#pragma unroll
    for (int i = 0; i < 4; ++i) {
        const int row = m0 + wy * 64 + i * 16 + c16;
#pragma unroll
        for (int j = 0; j < 4; ++j) {
            const int colb = n0 + wx * 64 + j * 16 + quad * 4;
            float4 bv = *(const float4*)&bias[colb];
            bf16x4_t o;
            o[0] = (__bf16)(acc[i][j][0] + bv.x);
            o[1] = (__bf16)(acc[i][j][1] + bv.y);
            o[2] = (__bf16)(acc[i][j][2] + bv.z);
            o[3] = (__bf16)(acc[i][j][3] + bv.w);
            *(bf16x4_t*)&C[(size_t)row * 512 + colb] = o;
        }
    }
}

// ---------------------------------------------------------------------------
// Scores GEMM + softmax partials. BK=32 double-buffered: LDS = 2*(128x32)*2
// matrices = 32 KB (+2 KB reduction) -> 34 KB -> 4 blocks/CU (vs 2 at BK=64).
// Counted vmcnt(4) prefetch kept; TLP from 16 waves/CU hides the shorter
// per-step latency cover. Swizzle: granule g of row r stored at position
// g ^ (r&3) ^ ((r>>2)&3) (per-quad 2-way bank aliasing = free, as BK=64).
// Staging chunk = 16 rows x 32 k = 1 KB = one wave-issue; LDS dest linear.
// Epilogue identical to r3/r6 (swapped-operand, lane owns one row).
// ---------------------------------------------------------------------------
__global__ __launch_bounds__(256) void gemm_scores(
    const __bf16* __restrict__ A,      // 512 x 512 (gatheredB)
    const __bf16* __restrict__ Bm,     // 40064(pad) x 512 (embB)
    __bf16* __restrict__ scB,          // 512 x SCLD
    float* __restrict__ pmax, float* __restrict__ psum)
{
    const int bid = blockIdx.x;
    const int xcd = bid & 7, k = bid >> 3;       // k: 0..159
    const int nt = xcd * 40 + (k >> 2);
    if (nt >= NT) return;
    const int m0 = (k & 3) * 128, n0 = nt * 128;

    __shared__ __bf16 As[2][128 * 32];   // 16 KB
    __shared__ __bf16 Bs[2][128 * 32];   // 16 KB
    __shared__ float redm[2][128], reds[2][128];   // 2 KB

    const int tid = threadIdx.x, lane = tid & 63, wave = tid >> 6;
    const int wy = wave >> 1, wx = wave & 1;
    const int lrow16 = lane >> 2;        // 0..15 row within staging chunk
    const int pos    = lane & 3;         // stored granule position
    const int quad = lane >> 4, c16 = lane & 15;

    // staging: 2 chunks (16 rows each) per matrix per thread
    const __bf16* aptr[2]; const __bf16* bptr[2]; int ldso[2];
#pragma unroll
    for (int i = 0; i < 2; ++i) {
        const int c = wave * 2 + i;                       // chunk 0..7
        const int g = pos ^ (lrow16 & 3) ^ (lrow16 >> 2); // source granule
        aptr[i] = A  + (size_t)(m0 + c * 16 + lrow16) * 512 + g * 8;
        bptr[i] = Bm + (size_t)(n0 + c * 16 + lrow16) * 512 + g * 8;
        ldso[i] = c * 512;                                // 16 rows * 32 elems
    }

    f32x4_t acc[4][4];
#pragma unroll
    for (int i = 0; i < 4; ++i)
#pragma unroll
        for (int j = 0; j < 4; ++j) acc[i][j] = (f32x4_t){0.f, 0.f, 0.f, 0.f};

    // prologue: stage K-step 0 into buffer 0
#pragma unroll
    for (int i = 0; i < 2; ++i) {
        async16(aptr[i], &As[0][ldso[i]]);
        async16(bptr[i], &Bs[0][ldso[i]]);
    }

    const int goff = ((quad ^ (c16 & 3) ^ (c16 >> 2))) * 8;  // read swizzle

#pragma unroll
    for (int t = 0; t < 16; ++t) {
        const int cur = t & 1;
        if (t < 15) {
            const int kk = (t + 1) * 32;
#pragma unroll
            for (int i = 0; i < 2; ++i) {
                async16(aptr[i] + kk, &As[cur ^ 1][ldso[i]]);
                async16(bptr[i] + kk, &Bs[cur ^ 1][ldso[i]]);
            }
            asm volatile("s_waitcnt vmcnt(4)" ::: "memory");
        } else {
            asm volatile("s_waitcnt vmcnt(0)" ::: "memory");
        }
        __builtin_amdgcn_s_barrier();
        bf16x8_t af[4], bfv[4];
#pragma unroll
        for (int i = 0; i < 4; ++i)
            af[i] = *(const bf16x8_t*)&As[cur][(wy * 64 + i * 16 + c16) * 32 + goff];
#pragma unroll
        for (int j = 0; j < 4; ++j)
            bfv[j] = *(const bf16x8_t*)&Bs[cur][(wx * 64 + j * 16 + c16) * 32 + goff];
#pragma unroll
        for (int i = 0; i < 4; ++i)
#pragma unroll
            for (int j = 0; j < 4; ++j)
                acc[i][j] = __builtin_amdgcn_mfma_f32_16x16x32_bf16(
                    bfv[j], af[i], acc[i][j], 0, 0, 0);   // swapped: rows=N, cols=M
        asm volatile("s_waitcnt lgkmcnt(0)" ::: "memory");
        __builtin_amdgcn_s_barrier();   // protect buf[cur] from next stage
    }

    // Epilogue: lane's 16 values all lie in row (m0+wy*64+i*16+c16);
    // cols n0+wx*64+j*16+quad*4 .. +3.  Lane-local softmax partials, then
    // cross-n lane combine (xor 16,32), then cross-wx combine via LDS.
    const bool tailb = (n0 + 128 > NCAND);
#pragma unroll
    for (int i = 0; i < 4; ++i) {
        const int lrw = wy * 64 + i * 16 + c16;       // tile-local row
        const size_t rowbase = (size_t)(m0 + lrw) * SCLD;
        float vs[4][4];
        float vmax = -FLT_MAX;
        float ssum = 0.f;
        if (!tailb) {
#pragma unroll
            for (int j = 0; j < 4; ++j) {
                const int nb = n0 + wx * 64 + j * 16 + quad * 4;
                bf16x4_t o;
#pragma unroll
                for (int rr = 0; rr < 4; ++rr) {
                    __bf16 xb = (__bf16)acc[i][j][rr];
                    o[rr] = xb;
                    float xr = (float)xb;
                    vs[j][rr] = xr;
                    vmax = fmaxf(vmax, xr);
                }
                *(bf16x4_t*)&scB[rowbase + nb] = o;
            }
#pragma unroll
            for (int j = 0; j < 4; ++j)
#pragma unroll
                for (int rr = 0; rr < 4; ++rr)
                    ssum += __expf(vs[j][rr] - vmax);
        } else {
            for (int j = 0; j < 4; ++j) {
                const int nb = n0 + wx * 64 + j * 16 + quad * 4;
                for (int rr = 0; rr < 4; ++rr) {
                    const int n = nb + rr;
                    __bf16 xb = (__bf16)acc[i][j][rr];
                    float xr = (float)xb;
                    if (n < NCAND) {
                        scB[rowbase + n] = xb;
                        vs[j][rr] = xr;
                        vmax = fmaxf(vmax, xr);
                    } else vs[j][rr] = -FLT_MAX;
                }
            }
            for (int j = 0; j < 4; ++j)
                for (int rr = 0; rr < 4; ++rr)
                    ssum += (vs[j][rr] > -FLT_MAX) ? __expf(vs[j][rr] - vmax) : 0.f;
        }
        // combine lanes {c16, c16+16, c16+32, c16+48} (same row, different n)
#pragma unroll
        for (int mk = 16; mk < 64; mk <<= 1) {
            float om = __shfl_xor(vmax, mk);
            float os = __shfl_xor(ssum, mk);
            float mm = fmaxf(vmax, om);
            ssum = ssum * __expf(vmax - mm) + os * __expf(om - mm);
            vmax = mm;
        }
        if (quad == 0) { redm[wx][lrw] = vmax; reds[wx][lrw] = ssum; }
    }
    __syncthreads();
    if (tid < 128) {
        float ma = redm[0][tid], sa = reds[0][tid];
        float mb = redm[1][tid], sb = reds[1][tid];
        float mm = fmaxf(ma, mb);
        float ss = sa * __expf(ma - mm) + sb * __expf(mb - mm);
        pmax[(size_t)(m0 + tid) * NT + nt] = mm;     // [row][nt] layout
        psum[(size_t)(m0 + tid) * NT + nt] = ss;
    }
}

// ---------------------------------------------------------------------------
// Attention: one block per (b,h); K/V/Q head-slices staged in LDS once.
// 256 threads = 16 queries x 16 lanes. tanh fused at write.
// ---------------------------------------------------------------------------
#define KPAD 72
__global__ __launch_bounds__(256) void attn_kernel(const __bf16* __restrict__ Qg,
                                                   const __bf16* __restrict__ K,
                                                   const __bf16* __restrict__ V,
                                                   __bf16* __restrict__ attnB) {
    const int b = blockIdx.x, h = blockIdx.y, t = threadIdx.x;
    __shared__ __bf16 Ks[128 * KPAD];
    __shared__ __bf16 Vs[128 * KPAD];
    __shared__ float  Qs[16 * 68];
    __shared__ float  P[16 * 130];

    for (int i = t; i < 1024; i += 256) {
        int row = i >> 3, cg = (i & 7) * 8;
        size_t gsrc = ((size_t)(b * S_CURR + row)) * D + h * DH + cg;
        *(bf16x8_t*)&Ks[row * KPAD + cg] = *(const bf16x8_t*)&K[gsrc];
        *(bf16x8_t*)&Vs[row * KPAD + cg] = *(const bf16x8_t*)&V[gsrc];
    }
    if (t < 128) {
        int q = t >> 3, cg = (t & 7) * 8;
        bf16x8_t qv = *(const bf16x8_t*)&Qg[((size_t)(b * NM + q)) * D + h * DH + cg];
#pragma unroll
        for (int u = 0; u < 8; ++u) Qs[q * 68 + cg + u] = (float)qv[u];
    }
    __syncthreads();

    const int q = t >> 4, i = t & 15;
    float sv[8];
    float lmax = -FLT_MAX;
#pragma unroll
    for (int z = 0; z < 8; ++z) {
        int kk = i + z * 16;
        float s = 0.f;
#pragma unroll
        for (int d0 = 0; d0 < DH; d0 += 8) {
            bf16x8_t kv = *(const bf16x8_t*)&Ks[kk * KPAD + d0];
#pragma unroll
            for (int u = 0; u < 8; ++u) s += Qs[q * 68 + d0 + u] * (float)kv[u];
        }
        sv[z] = s; lmax = fmaxf(lmax, s);
    }
#pragma unroll
    for (int mk = 1; mk < 16; mk <<= 1) lmax = fmaxf(lmax, __shfl_xor(lmax, mk));
    float lsum = 0.f;
#pragma unroll
    for (int z = 0; z < 8; ++z) {
        float e = __expf(sv[z] - lmax);
        P[q * 130 + i + z * 16] = e;
        lsum += e;
    }
#pragma unroll
    for (int mk = 1; mk < 16; mk <<= 1) lsum += __shfl_xor(lsum, mk);
    const float inv = 1.0f / lsum;

    // P[q][*] produced and consumed by the same wave (q-group within wave) —
    // wave-order LDS semantics make this safe without a block barrier.
    const int d = i * 4;
    float a0 = 0.f, a1 = 0.f, a2 = 0.f, a3 = 0.f;
    for (int kk = 0; kk < 128; ++kk) {
        float p = P[q * 130 + kk];
        bf16x4_t vv = *(const bf16x4_t*)&Vs[kk * KPAD + d];
        a0 += p * (float)vv[0]; a1 += p * (float)vv[1];
        a2 += p * (float)vv[2]; a3 += p * (float)vv[3];
    }
    __bf16* o = attnB + ((size_t)(b * NM + q)) * D + h * DH + d;
    o[0] = (__bf16)tanhf(a0 * inv); o[1] = (__bf16)tanhf(a1 * inv);
    o[2] = (__bf16)tanhf(a2 * inv); o[3] = (__bf16)tanhf(a3 * inv);
}

// ---------------------------------------------------------------------------
// Fused LSE + final output: one block per gathered row. Phase 1 reduces the
// row's 313 (pmax,psum) partials ([row][nt] layout -> coalesced); phase 2
// streams the row: out = f32(scB) - lse.
// ---------------------------------------------------------------------------
__global__ __launch_bounds__(256) void lse_final(const float* __restrict__ pmax,
                                                 const float* __restrict__ psum,
                                                 const __bf16* __restrict__ scB,
                                                 float* __restrict__ out) {
    const int row = blockIdx.x, t = threadIdx.x;
    __shared__ float ms[256], ss[256];
    float m = -FLT_MAX, s = 0.f;
    for (int i = t; i < NT; i += 256) {
        float om = pmax[(size_t)row * NT + i];
        float os = psum[(size_t)row * NT + i];
        float mm = fmaxf(m, om);
        s = s * __expf(m - mm) + os * __expf(om - mm);
        m = mm;
    }
    ms[t] = m; ss[t] = s;
    __syncthreads();
    for (int off = 128; off > 0; off >>= 1) {
        if (t < off) {
            float m1 = ms[t], s1 = ss[t], m2 = ms[t + off], s2 = ss[t + off];
            float mm = fmaxf(m1, m2);
            ms[t] = mm;
            ss[t] = s1 * __expf(m1 - mm) + s2 * __expf(m2 - mm);
        }
        __syncthreads();
    }
    const float l = ms[0] + logf(ss[0]);

    const __bf16* src = scB + (size_t)row * SCLD;
    float* o = out + (size_t)row * NCAND;
    for (int c0 = t * 8; c0 < NCAND; c0 += 256 * 8) {
        bf16x8_t v = *(const bf16x8_t*)(src + c0);   // SCLD pad keeps tail read in-bounds
        if (c0 + 8 <= NCAND) {
            *(float2*)(o + c0)     = make_float2((float)v[0] - l, (float)v[1] - l);
            *(float2*)(o + c0 + 2) = make_float2((float)v[2] - l, (float)v[3] - l);
            *(float2*)(o + c0 + 4) = make_float2((float)v[4] - l, (float)v[5] - l);
            *(float2*)(o + c0 + 6) = make_float2((float)v[6] - l, (float)v[7] - l);
        } else {
            for (int k2 = 0; k2 < NCAND - c0; ++k2) o[c0 + k2] = (float)v[k2] - l;
        }
    }
}

// ---------------------------------------------------------------------------
extern "C" void kernel_launch(void* const* d_in, const int* in_sizes, int n_in,
                              void* d_out, int out_size, void* d_ws, size_t ws_size,
                              hipStream_t stream) {
    const int*   mask_pos = (const int*)d_in[2];
    const int*   curr_idx = (const int*)d_in[3];
    const float* emb      = (const float*)d_in[5];
    const float* c_wq = (const float*)d_in[12];
    const float* c_bq = (const float*)d_in[13];
    const float* c_wk = (const float*)d_in[14];
    const float* c_bk = (const float*)d_in[15];
    const float* c_wv = (const float*)d_in[16];
    const float* c_bv = (const float*)d_in[17];
    const float* t2_w = (const float*)d_in[24];
    const float* t2_b = (const float*)d_in[25];
    float* out = (float*)d_out;

    char* w = (char*)d_ws;
    __bf16* embB  = (__bf16*)w;                           // 40064x512 bf16 = 41 MB
    __bf16* scB   = (__bf16*)(w + 41025536);              // 512x40064 bf16 = 41 MB
    __bf16* currB = scB;                                  // overlay (dead pre-scores)
    __bf16* Kf    = (__bf16*)(w + 41025536 + 4194304);
    __bf16* Vf    = (__bf16*)(w + 41025536 + 8388608);
    __bf16* Qg    = (__bf16*)(w + 41025536 + 12582912);
    __bf16* attnB = (__bf16*)(w + 41025536 + 13107200);
    __bf16* wqB   = (__bf16*)(w + 41025536 + 13631488);
    __bf16* wkB   = (__bf16*)(w + 41025536 + 14155776);
    __bf16* wvB   = (__bf16*)(w + 41025536 + 14680064);
    __bf16* t2wB  = (__bf16*)(w + 41025536 + 15204352);
    int*    qidx  = (int*)   (w + 41025536 + 15728640);
    __bf16* gatheredB = (__bf16*)(w + 82051072);
    float*  pmax  = (float*)(w + 82575360);
    float*  psum  = (float*)(w + 83216384);

    hipLaunchKernelGGL(prep_kernel, dim3(14609), dim3(256), 0, stream,
                       emb, c_wq, c_wk, c_wv, t2_w, embB, wqB, wkB, wvB, t2wB,
                       curr_idx, currB, mask_pos, qidx);
    // K (z=0), V (z=1), Q-gathered (z=2, only 4 M-tiles) in one dispatch
    hipLaunchKernelGGL(gemm_bf, dim3(32, 4, 3), dim3(256), 0, stream,
                       currB, wkB, c_bk, Kf, wvB, c_bv, Vf, wqB, c_bq, Qg, qidx);
    hipLaunchKernelGGL(attn_kernel, dim3(B, H), dim3(256), 0, stream,
                       Qg, Kf, Vf, attnB);
    hipLaunchKernelGGL(gemm_bf, dim3(4, 4, 1), dim3(256), 0, stream,
                       attnB, t2wB, t2_b, gatheredB,
                       t2wB, t2_b, gatheredB, t2wB, t2_b, gatheredB,
                       (const int*)nullptr);
    hipLaunchKernelGGL(gemm_scores, dim3(1280), dim3(256), 0, stream,
                       gatheredB, embB, scB, pmax, psum);
    hipLaunchKernelGGL(lse_final, dim3(MG), dim3(256), 0, stream,
                       pmax, psum, scB, out);
}

// Round 8
// 283.944 us; speedup vs baseline: 1.0704x; 1.0202x over previous
//
#include <hip/hip_runtime.h>
#include <hip/hip_bf16.h>
#include <math.h>
#include <float.h>

#define B       32
#define S_CURR  128
#define D       512
#define H       8
#define DH      64
#define NM      16
#define NCAND   39998          // emb[2:]
#define MG      (B * NM)       // 512 gathered rows
#define SCLD    40064          // col stride of scB
#define NT      313            // ceil(NCAND/128) N-tiles

typedef __bf16 bf16x8_t __attribute__((ext_vector_type(8)));
typedef __bf16 bf16x4_t __attribute__((ext_vector_type(4)));
typedef __bf16 bf16x2_t __attribute__((ext_vector_type(2)));
typedef float  f32x4_t  __attribute__((ext_vector_type(4)));

typedef __attribute__((address_space(3))) unsigned int lds_u32_t;
typedef const __attribute__((address_space(1))) unsigned int gbl_u32_t;

__device__ __forceinline__ void async16(const void* g, void* l) {
    __builtin_amdgcn_global_load_lds((gbl_u32_t*)g, (lds_u32_t*)l, 16, 0, 0);
}

// ---------------------------------------------------------------------------
// Prep kernel (embB pass ELIMINATED — gemm_scores reads emb f32 directly):
// bx < 512 -> weight mats f32->bf16; 512 <= bx < 4608 -> currB; 4608 -> qidx.
// ---------------------------------------------------------------------------
__global__ __launch_bounds__(256) void prep_kernel(
    const float* __restrict__ emb,
    const float* __restrict__ wq, const float* __restrict__ wk,
    const float* __restrict__ wv, const float* __restrict__ t2w,
    __bf16* __restrict__ wqB, __bf16* __restrict__ wkB,
    __bf16* __restrict__ wvB, __bf16* __restrict__ t2wB,
    const int* __restrict__ curr_idx, __bf16* __restrict__ currB,
    const int* __restrict__ mask_pos, int* __restrict__ qidx)
{
    int bx = blockIdx.x;
    if (bx < 512) {
        int w = bx >> 7;
        size_t base = (size_t)(bx & 127) * 2048;
        const float* src = (w == 0) ? wq : (w == 1) ? wk : (w == 2) ? wv : t2w;
        __bf16* dst = (w == 0) ? wqB : (w == 1) ? wkB : (w == 2) ? wvB : t2wB;
        size_t i = base + (size_t)threadIdx.x * 8;
        float4 a = *(const float4*)(src + i);
        float4 b = *(const float4*)(src + i + 4);
        bf16x8_t v;
        v[0] = (__bf16)a.x; v[1] = (__bf16)a.y; v[2] = (__bf16)a.z; v[3] = (__bf16)a.w;
        v[4] = (__bf16)b.x; v[5] = (__bf16)b.y; v[6] = (__bf16)b.z; v[7] = (__bf16)b.w;
        *(bf16x8_t*)(dst + i) = v;
        return;
    }
    if (bx == 4608) {
        int r = threadIdx.x;
        qidx[r] = (r >> 4) * S_CURR + mask_pos[r];
        r += 256;
        qidx[r] = (r >> 4) * S_CURR + mask_pos[r];
        return;
    }
    int bs = bx - 512;
    int s = bs & (S_CURR - 1);
    int g = curr_idx[bs];
    const float* e = emb + (size_t)g * D;
    __bf16* o = currB + (size_t)bs * D;
    int d = threadIdx.x * 2;
    float div = __expf(-(float)d * (9.210340371976184f / 512.0f));
    float ang = (float)s * div;
    float2 ev = *(const float2*)(e + d);
    bf16x2_t ov;
    ov[0] = (__bf16)(ev.x + __sinf(ang));
    ov[1] = (__bf16)(ev.y + __cosf(ang));
    *(bf16x2_t*)(o + d) = ov;
}

// ---------------------------------------------------------------------------
// bf16 GEMM, swizzled-LDS, double-buffered counted-vmcnt prefetch.
// C = A @ W^T + bias, K=512, N=512. Unchanged from r7 (measured-good).
// ---------------------------------------------------------------------------
__global__ __launch_bounds__(256) void gemm_bf(
    const __bf16* __restrict__ A,
    const __bf16* __restrict__ W0, const float* __restrict__ b0, __bf16* __restrict__ C0,
    const __bf16* __restrict__ W1, const float* __restrict__ b1, __bf16* __restrict__ C1,
    const __bf16* __restrict__ W2, const float* __restrict__ b2, __bf16* __restrict__ C2,
    const int* __restrict__ rowidx)
{
    const int z = blockIdx.z;
    if (z == 2 && blockIdx.x >= 4) return;   // Q problem has M=512 only
    const __bf16* W = (z == 0) ? W0 : (z == 1) ? W1 : W2;
    const float* bias = (z == 0) ? b0 : (z == 1) ? b1 : b2;
    __bf16* C = (z == 0) ? C0 : (z == 1) ? C1 : C2;

    __shared__ __bf16 As[2][128 * 64];
    __shared__ __bf16 Bs[2][128 * 64];

    const int tid = threadIdx.x, lane = tid & 63, wave = tid >> 6;
    const int wy = wave >> 1, wx = wave & 1;
    const int m0 = blockIdx.x * 128, n0 = blockIdx.y * 128;
    const int lrow = lane >> 3;
    const int lcol = (((lane & 7) ^ lrow) & 7) * 8;   // swizzled source column

    const __bf16* aptr[4]; const __bf16* bptr[4];
#pragma unroll
    for (int i = 0; i < 4; ++i) {
        int chunk = wave * 4 + i;
        int ar = m0 + chunk * 8 + lrow;
        if (z == 2) ar = rowidx[ar];
        aptr[i] = A + (size_t)ar * 512 + lcol;
        bptr[i] = W + (size_t)(n0 + chunk * 8 + lrow) * 512 + lcol;
    }

    f32x4_t acc[4][4];
#pragma unroll
    for (int i = 0; i < 4; ++i)
#pragma unroll
        for (int j = 0; j < 4; ++j) acc[i][j] = (f32x4_t){0.f, 0.f, 0.f, 0.f};

    const int l7 = lane & 7, quad = lane >> 4, c16 = lane & 15;

    // prologue: stage K-step 0 into buffer 0
#pragma unroll
    for (int i = 0; i < 4; ++i) {
        int chunk = wave * 4 + i;
        async16(aptr[i], &As[0][chunk * 512]);
        async16(bptr[i], &Bs[0][chunk * 512]);
    }

#pragma unroll
    for (int t = 0; t < 8; ++t) {
        const int cur = t & 1;
        if (t < 7) {
            const int kk = (t + 1) * 64;
#pragma unroll
            for (int i = 0; i < 4; ++i) {
                int chunk = wave * 4 + i;
                async16(aptr[i] + kk, &As[cur ^ 1][chunk * 512]);
                async16(bptr[i] + kk, &Bs[cur ^ 1][chunk * 512]);
            }
            asm volatile("s_waitcnt vmcnt(8)" ::: "memory");
        } else {
            asm volatile("s_waitcnt vmcnt(0)" ::: "memory");
        }
        __builtin_amdgcn_s_barrier();
#pragma unroll
        for (int kb = 0; kb < 2; ++kb) {
            const int goff = (((kb * 4 + quad) ^ l7)) * 8;
            bf16x8_t af[4], bfv[4];
#pragma unroll
            for (int i = 0; i < 4; ++i)
                af[i] = *(const bf16x8_t*)&As[cur][(wy * 64 + i * 16 + c16) * 64 + goff];
#pragma unroll
            for (int j = 0; j < 4; ++j)
                bfv[j] = *(const bf16x8_t*)&Bs[cur][(wx * 64 + j * 16 + c16) * 64 + goff];
#pragma unroll
            for (int i = 0; i < 4; ++i)
#pragma unroll
                for (int j = 0; j < 4; ++j)
                    acc[i][j] = __builtin_amdgcn_mfma_f32_16x16x32_bf16(
                        bfv[j], af[i], acc[i][j], 0, 0, 0);   // swapped: rows=N, cols=M
        }
        asm volatile("s_waitcnt lgkmcnt(0)" ::: "memory");
        __builtin_amdgcn_s_barrier();   // protect buf[cur] from next stage
    }

    // Swapped C/D layout: per (i,j) a lane holds cols colb..colb+3 of row
    // (m0 + wy*64 + i*16 + c16). Vectorized bf16x4 stores, float4 bias.
#pragma unroll
    for (int i = 0; i < 4; ++i) {
        const int row = m0 + wy * 64 + i * 16 + c16;
#pragma unroll
        for (int j = 0; j < 4; ++j) {
            const int colb = n0 + wx * 64 + j * 16 + quad * 4;
            float4 bv = *(const float4*)&bias[colb];
            bf16x4_t o;
            o[0] = (__bf16)(acc[i][j][0] + bv.x);
            o[1] = (__bf16)(acc[i][j][1] + bv.y);
            o[2] = (__bf16)(acc[i][j][2] + bv.z);
            o[3] = (__bf16)(acc[i][j][3] + bv.w);
            *(bf16x4_t*)&C[(size_t)row * 512 + colb] = o;
        }
    }
}

// ---------------------------------------------------------------------------
// Scores GEMM + softmax partials. BK=32, 4 blocks/CU (34 KB LDS) as r7, but
// B is read DIRECTLY from emb (f32) with fused bf16 conversion: reg-staged
// (T14 issue-early/write-late), loads one K-step ahead. Stored LDS layout
// identical to r7's async16 path, so read side + MFMA loop unchanged.
// Per-thread VM FIFO: [B(t+1)x4] at step entry; +A(t+1)x2 -> vmcnt(2)
// retires B; ds_write; +B(t+2)x4 -> end vmcnt(4) retires A. A (gatheredB,
// bf16) keeps global_load_lds. Tail-tile B rows clamped (epilogue masks).
// ---------------------------------------------------------------------------
__global__ __launch_bounds__(256) void gemm_scores(
    const __bf16* __restrict__ A,      // 512 x 512 (gatheredB)
    const float* __restrict__ emb2,    // emb + 2*D : NCAND x 512 f32
    __bf16* __restrict__ scB,          // 512 x SCLD
    float* __restrict__ pmax, float* __restrict__ psum)
{
    const int bid = blockIdx.x;
    const int xcd = bid & 7, k = bid >> 3;       // k: 0..159
    const int nt = xcd * 40 + (k >> 2);
    if (nt >= NT) return;
    const int m0 = (k & 3) * 128, n0 = nt * 128;

    __shared__ __bf16 As[2][128 * 32];   // 16 KB
    __shared__ __bf16 Bs[2][128 * 32];   // 16 KB
    __shared__ float redm[2][128], reds[2][128];   // 2 KB

    const int tid = threadIdx.x, lane = tid & 63, wave = tid >> 6;
    const int wy = wave >> 1, wx = wave & 1;
    const int lrow16 = lane >> 2;        // 0..15 row within staging chunk
    const int pos    = lane & 3;         // stored granule slot
    const int quad = lane >> 4, c16 = lane & 15;
    const int g = pos ^ (lrow16 & 3) ^ (lrow16 >> 2);   // source granule

    const __bf16* aptr[2]; const float* bptr[2]; int aldso[2], bldso[2];
#pragma unroll
    for (int i = 0; i < 2; ++i) {
        const int c = wave * 2 + i;                       // chunk 0..7
        aptr[i]  = A + (size_t)(m0 + c * 16 + lrow16) * 512 + g * 8;
        int brow = n0 + c * 16 + lrow16;
        if (brow >= NCAND) brow = NCAND - 1;              // clamp tail tile
        bptr[i]  = emb2 + (size_t)brow * 512 + g * 8;
        aldso[i] = c * 512;                               // async16 dest (lane-scattered)
        bldso[i] = c * 512 + lrow16 * 32 + pos * 8;       // explicit ds_write dest
    }

    f32x4_t acc[4][4];
#pragma unroll
    for (int i = 0; i < 4; ++i)
#pragma unroll
        for (int j = 0; j < 4; ++j) acc[i][j] = (f32x4_t){0.f, 0.f, 0.f, 0.f};

    float4 rb[2][2];
    // prologue: B(0) loads, A(0) asyncs -> queue [B0x4, A0x2]
#pragma unroll
    for (int i = 0; i < 2; ++i) {
        rb[i][0] = *(const float4*)(bptr[i]);
        rb[i][1] = *(const float4*)(bptr[i] + 4);
    }
#pragma unroll
    for (int i = 0; i < 2; ++i)
        async16(aptr[i], &As[0][aldso[i]]);
    asm volatile("s_waitcnt vmcnt(2)" ::: "memory");   // B(0) regs ready
#pragma unroll
    for (int i = 0; i < 2; ++i) {
        bf16x8_t bw;
        bw[0] = (__bf16)rb[i][0].x; bw[1] = (__bf16)rb[i][0].y;
        bw[2] = (__bf16)rb[i][0].z; bw[3] = (__bf16)rb[i][0].w;
        bw[4] = (__bf16)rb[i][1].x; bw[5] = (__bf16)rb[i][1].y;
        bw[6] = (__bf16)rb[i][1].z; bw[7] = (__bf16)rb[i][1].w;
        *(bf16x8_t*)&Bs[0][bldso[i]] = bw;
    }
#pragma unroll
    for (int i = 0; i < 2; ++i) {                      // issue B(1)
        rb[i][0] = *(const float4*)(bptr[i] + 32);
        rb[i][1] = *(const float4*)(bptr[i] + 36);
    }
    asm volatile("s_waitcnt vmcnt(4)" ::: "memory");   // A(0) landed (B1 in flight)
    asm volatile("s_waitcnt lgkmcnt(0)" ::: "memory");
    __builtin_amdgcn_s_barrier();

    const int goff = ((quad ^ (c16 & 3) ^ (c16 >> 2))) * 8;  // read swizzle

#pragma unroll
    for (int t = 0; t < 16; ++t) {
        const int cur = t & 1;
        if (t < 15) {
#pragma unroll
            for (int i = 0; i < 2; ++i)                // A(t+1) async -> As[nxt]
                async16(aptr[i] + (t + 1) * 32, &As[cur ^ 1][aldso[i]]);
            asm volatile("s_waitcnt vmcnt(2)" ::: "memory");   // B(t+1) regs ready
#pragma unroll
            for (int i = 0; i < 2; ++i) {              // ds_write B(t+1) -> Bs[nxt]
                bf16x8_t bw;
                bw[0] = (__bf16)rb[i][0].x; bw[1] = (__bf16)rb[i][0].y;
                bw[2] = (__bf16)rb[i][0].z; bw[3] = (__bf16)rb[i][0].w;
                bw[4] = (__bf16)rb[i][1].x; bw[5] = (__bf16)rb[i][1].y;
                bw[6] = (__bf16)rb[i][1].z; bw[7] = (__bf16)rb[i][1].w;
                *(bf16x8_t*)&Bs[cur ^ 1][bldso[i]] = bw;
            }
            if (t < 14) {
#pragma unroll
                for (int i = 0; i < 2; ++i) {          // issue B(t+2)
                    rb[i][0] = *(const float4*)(bptr[i] + (t + 2) * 32);
                    rb[i][1] = *(const float4*)(bptr[i] + (t + 2) * 32 + 4);
                }
            }
        }
        bf16x8_t af[4], bfv[4];
#pragma unroll
        for (int i = 0; i < 4; ++i)
            af[i] = *(const bf16x8_t*)&As[cur][(wy * 64 + i * 16 + c16) * 32 + goff];
#pragma unroll
        for (int j = 0; j < 4; ++j)
            bfv[j] = *(const bf16x8_t*)&Bs[cur][(wx * 64 + j * 16 + c16) * 32 + goff];
#pragma unroll
        for (int i = 0; i < 4; ++i)
#pragma unroll
            for (int j = 0; j < 4; ++j)
                acc[i][j] = __builtin_amdgcn_mfma_f32_16x16x32_bf16(
                    bfv[j], af[i], acc[i][j], 0, 0, 0);   // swapped: rows=N, cols=M
        if (t < 14)      asm volatile("s_waitcnt vmcnt(4)" ::: "memory"); // retire A(t+1)
        else if (t == 14) asm volatile("s_waitcnt vmcnt(0)" ::: "memory"); // retire A(15)
        asm volatile("s_waitcnt lgkmcnt(0)" ::: "memory");
        __builtin_amdgcn_s_barrier();
    }

    // Epilogue: lane's 16 values all lie in row (m0+wy*64+i*16+c16);
    // cols n0+wx*64+j*16+quad*4 .. +3.  Lane-local softmax partials, then
    // cross-n lane combine (xor 16,32), then cross-wx combine via LDS.
    const bool tailb = (n0 + 128 > NCAND);
#pragma unroll
    for (int i = 0; i < 4; ++i) {
        const int lrw = wy * 64 + i * 16 + c16;       // tile-local row
        const size_t rowbase = (size_t)(m0 + lrw) * SCLD;
        float vs[4][4];
        float vmax = -FLT_MAX;
        float ssum = 0.f;
        if (!tailb) {
#pragma unroll
            for (int j = 0; j < 4; ++j) {
                const int nb = n0 + wx * 64 + j * 16 + quad * 4;
                bf16x4_t o;
#pragma unroll
                for (int rr = 0; rr < 4; ++rr) {
                    __bf16 xb = (__bf16)acc[i][j][rr];
                    o[rr] = xb;
                    float xr = (float)xb;
                    vs[j][rr] = xr;
                    vmax = fmaxf(vmax, xr);
                }
                *(bf16x4_t*)&scB[rowbase + nb] = o;
            }
#pragma unroll
            for (int j = 0; j < 4; ++j)
#pragma unroll
                for (int rr = 0; rr < 4; ++rr)
                    ssum += __expf(vs[j][rr] - vmax);
        } else {
            for (int j = 0; j < 4; ++j) {
                const int nb = n0 + wx * 64 + j * 16 + quad * 4;
                for (int rr = 0; rr < 4; ++rr) {
                    const int n = nb + rr;
                    __bf16 xb = (__bf16)acc[i][j][rr];
                    float xr = (float)xb;
                    if (n < NCAND) {
                        scB[rowbase + n] = xb;
                        vs[j][rr] = xr;
                        vmax = fmaxf(vmax, xr);
                    } else vs[j][rr] = -FLT_MAX;
                }
            }
            for (int j = 0; j < 4; ++j)
                for (int rr = 0; rr < 4; ++rr)
                    ssum += (vs[j][rr] > -FLT_MAX) ? __expf(vs[j][rr] - vmax) : 0.f;
        }
        // combine lanes {c16, c16+16, c16+32, c16+48} (same row, different n)
#pragma unroll
        for (int mk = 16; mk < 64; mk <<= 1) {
            float om = __shfl_xor(vmax, mk);
            float os = __shfl_xor(ssum, mk);
            float mm = fmaxf(vmax, om);
            ssum = ssum * __expf(vmax - mm) + os * __expf(om - mm);
            vmax = mm;
        }
        if (quad == 0) { redm[wx][lrw] = vmax; reds[wx][lrw] = ssum; }
    }
    __syncthreads();
    if (tid < 128) {
        float ma = redm[0][tid], sa = reds[0][tid];
        float mb = redm[1][tid], sb = reds[1][tid];
        float mm = fmaxf(ma, mb);
        float ss = sa * __expf(ma - mm) + sb * __expf(mb - mm);
        pmax[(size_t)(m0 + tid) * NT + nt] = mm;     // [row][nt] layout
        psum[(size_t)(m0 + tid) * NT + nt] = ss;
    }
}

// ---------------------------------------------------------------------------
// Attention: one block per (b,h); K/V/Q head-slices staged in LDS once.
// 256 threads = 16 queries x 16 lanes. tanh fused at write.
// ---------------------------------------------------------------------------
#define KPAD 72
__global__ __launch_bounds__(256) void attn_kernel(const __bf16* __restrict__ Qg,
                                                   const __bf16* __restrict__ K,
                                                   const __bf16* __restrict__ V,
                                                   __bf16* __restrict__ attnB) {
    const int b = blockIdx.x, h = blockIdx.y, t = threadIdx.x;
    __shared__ __bf16 Ks[128 * KPAD];
    __shared__ __bf16 Vs[128 * KPAD];
    __shared__ float  Qs[16 * 68];
    __shared__ float  P[16 * 130];

    for (int i = t; i < 1024; i += 256) {
        int row = i >> 3, cg = (i & 7) * 8;
        size_t gsrc = ((size_t)(b * S_CURR + row)) * D + h * DH + cg;
        *(bf16x8_t*)&Ks[row * KPAD + cg] = *(const bf16x8_t*)&K[gsrc];
        *(bf16x8_t*)&Vs[row * KPAD + cg] = *(const bf16x8_t*)&V[gsrc];
    }
    if (t < 128) {
        int q = t >> 3, cg = (t & 7) * 8;
        bf16x8_t qv = *(const bf16x8_t*)&Qg[((size_t)(b * NM + q)) * D + h * DH + cg];
#pragma unroll
        for (int u = 0; u < 8; ++u) Qs[q * 68 + cg + u] = (float)qv[u];
    }
    __syncthreads();

    const int q = t >> 4, i = t & 15;
    float sv[8];
    float lmax = -FLT_MAX;
#pragma unroll
    for (int z = 0; z < 8; ++z) {
        int kk = i + z * 16;
        float s = 0.f;
#pragma unroll
        for (int d0 = 0; d0 < DH; d0 += 8) {
            bf16x8_t kv = *(const bf16x8_t*)&Ks[kk * KPAD + d0];
#pragma unroll
            for (int u = 0; u < 8; ++u) s += Qs[q * 68 + d0 + u] * (float)kv[u];
        }
        sv[z] = s; lmax = fmaxf(lmax, s);
    }
#pragma unroll
    for (int mk = 1; mk < 16; mk <<= 1) lmax = fmaxf(lmax, __shfl_xor(lmax, mk));
    float lsum = 0.f;
#pragma unroll
    for (int z = 0; z < 8; ++z) {
        float e = __expf(sv[z] - lmax);
        P[q * 130 + i + z * 16] = e;
        lsum += e;
    }
#pragma unroll
    for (int mk = 1; mk < 16; mk <<= 1) lsum += __shfl_xor(lsum, mk);
    const float inv = 1.0f / lsum;

    // P[q][*] produced and consumed by the same wave (q-group within wave) —
    // wave-order LDS semantics make this safe without a block barrier.
    const int d = i * 4;
    float a0 = 0.f, a1 = 0.f, a2 = 0.f, a3 = 0.f;
    for (int kk = 0; kk < 128; ++kk) {
        float p = P[q * 130 + kk];
        bf16x4_t vv = *(const bf16x4_t*)&Vs[kk * KPAD + d];
        a0 += p * (float)vv[0]; a1 += p * (float)vv[1];
        a2 += p * (float)vv[2]; a3 += p * (float)vv[3];
    }
    __bf16* o = attnB + ((size_t)(b * NM + q)) * D + h * DH + d;
    o[0] = (__bf16)tanhf(a0 * inv); o[1] = (__bf16)tanhf(a1 * inv);
    o[2] = (__bf16)tanhf(a2 * inv); o[3] = (__bf16)tanhf(a3 * inv);
}

// ---------------------------------------------------------------------------
// Fused LSE + final output: one block per gathered row. Phase 1 reduces the
// row's 313 (pmax,psum) partials ([row][nt] layout -> coalesced); phase 2
// streams the row: out = f32(scB) - lse.
// ---------------------------------------------------------------------------
__global__ __launch_bounds__(256) void lse_final(const float* __restrict__ pmax,
                                                 const float* __restrict__ psum,
                                                 const __bf16* __restrict__ scB,
                                                 float* __restrict__ out) {
    const int row = blockIdx.x, t = threadIdx.x;
    __shared__ float ms[256], ss[256];
    float m = -FLT_MAX, s = 0.f;
    for (int i = t; i < NT; i += 256) {
        float om = pmax[(size_t)row * NT + i];
        float os = psum[(size_t)row * NT + i];
        float mm = fmaxf(m, om);
        s = s * __expf(m - mm) + os * __expf(om - mm);
        m = mm;
    }
    ms[t] = m; ss[t] = s;
    __syncthreads();
    for (int off = 128; off > 0; off >>= 1) {
        if (t < off) {
            float m1 = ms[t], s1 = ss[t], m2 = ms[t + off], s2 = ss[t + off];
            float mm = fmaxf(m1, m2);
            ms[t] = mm;
            ss[t] = s1 * __expf(m1 - mm) + s2 * __expf(m2 - mm);
        }
        __syncthreads();
    }
    const float l = ms[0] + logf(ss[0]);

    const __bf16* src = scB + (size_t)row * SCLD;
    float* o = out + (size_t)row * NCAND;
    for (int c0 = t * 8; c0 < NCAND; c0 += 256 * 8) {
        bf16x8_t v = *(const bf16x8_t*)(src + c0);   // SCLD pad keeps tail read in-bounds
        if (c0 + 8 <= NCAND) {
            *(float2*)(o + c0)     = make_float2((float)v[0] - l, (float)v[1] - l);
            *(float2*)(o + c0 + 2) = make_float2((float)v[2] - l, (float)v[3] - l);
            *(float2*)(o + c0 + 4) = make_float2((float)v[4] - l, (float)v[5] - l);
            *(float2*)(o + c0 + 6) = make_float2((float)v[6] - l, (float)v[7] - l);
        } else {
            for (int k2 = 0; k2 < NCAND - c0; ++k2) o[c0 + k2] = (float)v[k2] - l;
        }
    }
}

// ---------------------------------------------------------------------------
extern "C" void kernel_launch(void* const* d_in, const int* in_sizes, int n_in,
                              void* d_out, int out_size, void* d_ws, size_t ws_size,
                              hipStream_t stream) {
    const int*   mask_pos = (const int*)d_in[2];
    const int*   curr_idx = (const int*)d_in[3];
    const float* emb      = (const float*)d_in[5];
    const float* c_wq = (const float*)d_in[12];
    const float* c_bq = (const float*)d_in[13];
    const float* c_wk = (const float*)d_in[14];
    const float* c_bk = (const float*)d_in[15];
    const float* c_wv = (const float*)d_in[16];
    const float* c_bv = (const float*)d_in[17];
    const float* t2_w = (const float*)d_in[24];
    const float* t2_b = (const float*)d_in[25];
    float* out = (float*)d_out;

    char* w = (char*)d_ws;
    __bf16* scB   = (__bf16*)(w + 41025536);              // 512x40064 bf16 = 41 MB
    __bf16* currB = scB;                                  // overlay (dead pre-scores)
    __bf16* Kf    = (__bf16*)(w + 41025536 + 4194304);
    __bf16* Vf    = (__bf16*)(w + 41025536 + 8388608);
    __bf16* Qg    = (__bf16*)(w + 41025536 + 12582912);
    __bf16* attnB = (__bf16*)(w + 41025536 + 13107200);
    __bf16* wqB   = (__bf16*)(w + 41025536 + 13631488);
    __bf16* wkB   = (__bf16*)(w + 41025536 + 14155776);
    __bf16* wvB   = (__bf16*)(w + 41025536 + 14680064);
    __bf16* t2wB  = (__bf16*)(w + 41025536 + 15204352);
    int*    qidx  = (int*)   (w + 41025536 + 15728640);
    __bf16* gatheredB = (__bf16*)(w + 82051072);
    float*  pmax  = (float*)(w + 82575360);
    float*  psum  = (float*)(w + 83216384);

    hipLaunchKernelGGL(prep_kernel, dim3(4609), dim3(256), 0, stream,
                       emb, c_wq, c_wk, c_wv, t2_w, wqB, wkB, wvB, t2wB,
                       curr_idx, currB, mask_pos, qidx);
    // K (z=0), V (z=1), Q-gathered (z=2, only 4 M-tiles) in one dispatch
    hipLaunchKernelGGL(gemm_bf, dim3(32, 4, 3), dim3(256), 0, stream,
                       currB, wkB, c_bk, Kf, wvB, c_bv, Vf, wqB, c_bq, Qg, qidx);
    hipLaunchKernelGGL(attn_kernel, dim3(B, H), dim3(256), 0, stream,
                       Qg, Kf, Vf, attnB);
    hipLaunchKernelGGL(gemm_bf, dim3(4, 4, 1), dim3(256), 0, stream,
                       attnB, t2wB, t2_b, gatheredB,
                       t2wB, t2_b, gatheredB, t2wB, t2_b, gatheredB,
                       (const int*)nullptr);
    hipLaunchKernelGGL(gemm_scores, dim3(1280), dim3(256), 0, stream,
                       gatheredB, emb + 2 * D, scB, pmax, psum);
    hipLaunchKernelGGL(lse_final, dim3(MG), dim3(256), 0, stream,
                       pmax, psum, scB, out);
}